// Round 1
// baseline (993.789 us; speedup 1.0000x reference)
//
#include <hip/hip_runtime.h>
#include <hip/hip_fp16.h>

// ColorDeformConv2d — round 5: single block per (h,b), atomic-free.
// prep: repack weights into MFMA frag-order bf16 (unchanged)
// k2:   fused = 1x1 conv (MFMA), writes fused2 channel-major bf16 (unchanged)
// k3:   per (h,b): full M=640 U-GEMM (acc[5][2]/wave, 8 waves), pm GEMM fused
//       (waves 0-3 carry one extra accumulator on the same staged B chunks),
//       tables built once from in-LDS f32 pm result, epilogue
//       tanh+bilinear-sample+modulate in regs, then 5-phase scatter->out-GEMM
//       with oa accumulated in regs -> plain stores (NO atomics, no memset).
//       Grid XCD-banded: xcd = id&7 owns a contiguous 16-row h band.
//
// ws (u16 elems): A_c[20mt][36ks][64l][8] @0 (368640), A_pm @368640 (18432),
// A_conv[2][40][64][8] @387072 (40960), Wcd row-major @428032 (8192),
// fused2 @436224 (4*64*16384). Total 9.3 MB (u workspace removed).

typedef __attribute__((ext_vector_type(8))) __bf16 bf16x8;
typedef __attribute__((ext_vector_type(16))) float f32x16;
#define MFMA32(a, b, c) __builtin_amdgcn_mfma_f32_32x32x16_bf16((a), (b), (c), 0, 0, 0)

#define WS_AC    0
#define WS_APM   368640
#define WS_ACONV 387072
#define WS_WCD   428032
#define WS_F2    436224

__device__ __forceinline__ unsigned short f2bf(float f) {
    unsigned u = __float_as_uint(f);
    return (unsigned short)((u + 0x7FFFu + ((u >> 16) & 1u)) >> 16);   // RNE
}
__device__ __forceinline__ float bf2f(unsigned short s) {
    return __uint_as_float(((unsigned)s) << 16);
}
__device__ __forceinline__ float fast_rcp(float x) {
#if __has_builtin(__builtin_amdgcn_rcpf)
    return __builtin_amdgcn_rcpf(x);
#else
    return 1.0f / x;
#endif
}
__device__ __forceinline__ float fast_tanh(float x) {
    float t = __expf(2.0f * x);
    return 1.0f - 2.0f * fast_rcp(t + 1.0f);
}
__device__ __forceinline__ float fast_sigmoid(float x) {
    return fast_rcp(1.0f + __expf(-x));
}

// ---------------- prep: weight repack to frag-order bf16 ----------------
__global__ void prep_kernel(const float* __restrict__ w_c, const float* __restrict__ w_p,
                            const float* __restrict__ w_m, const float* __restrict__ w_conv,
                            const float* __restrict__ w_cd, unsigned short* __restrict__ ws) {
    int i = blockIdx.x * 256 + threadIdx.x;
    if (i >= 436224) return;
    float val;
    if (i < WS_APM) {                       // A_c: row=gmt*32+(l&31), k'=ks*16+(l>>5)*8+j
        int t = i, j = t & 7, l = (t >> 3) & 63, r = t >> 9, ks = r % 36, gmt = r / 36;
        int row = gmt * 32 + (l & 31);
        int kp = ks * 16 + (l >> 5) * 8 + j, tap = kp >> 6, ci = kp & 63;
        val = (row < 576) ? w_c[row * 576 + ci * 9 + tap] : 0.0f;
    } else if (i < WS_ACONV) {              // A_pm: rows 0-17 w_p, 18-26 w_m
        int t = i - WS_APM, j = t & 7, l = (t >> 3) & 63, ks = t >> 9;
        int row = l & 31;
        int kp = ks * 16 + (l >> 5) * 8 + j, tap = kp >> 6, ci = kp & 63;
        val = (row < 18) ? w_p[row * 576 + ci * 9 + tap]
            : (row < 27) ? w_m[(row - 18) * 576 + ci * 9 + tap] : 0.0f;
    } else if (i < WS_WCD) {                // A_conv: k = U-row (natural order)
        int t = i - WS_ACONV, j = t & 7, l = (t >> 3) & 63, r = t >> 9;
        int gks = r % 40, ocT = r / 40;
        int oc = ocT * 32 + (l & 31);
        int krow = gks * 16 + (l >> 5) * 8 + j;
        val = (krow < 576) ? w_conv[oc * 576 + krow] : 0.0f;
    } else {                                // Wcd row-major [64][128]
        val = w_cd[i - WS_WCD];
    }
    ws[i] = f2bf(val);
}

// ---------------- shared: im2col B-stage (32 k' x 128 px, frag-order) ------
template <int TPB>
__device__ __forceinline__ void stage_B(char* Bst, const unsigned short* f2b,
                                        int h, int chunk, int tid) {
    int tap = chunk >> 1, cih = (chunk & 1) * 32;
    int dh = tap / 3 - 1, dw = tap % 3 - 1;
    int hs = h + dh;
    #pragma unroll
    for (int it = 0; it < 512 / TPB; ++it) {
        int task = it * TPB + tid;          // 512 tasks: kg(4) x px(128)
        int kg = task >> 7, px = task & 127;
        int wsrc = px + dw;
        unsigned short v[8];
        if (((unsigned)hs < 128u) && ((unsigned)wsrc < 128u)) {
            const unsigned short* r = f2b + ((cih + kg * 8) << 14) + (hs << 7) + wsrc;
            #pragma unroll
            for (int j = 0; j < 8; ++j) v[j] = r[j << 14];
        } else {
            #pragma unroll
            for (int j = 0; j < 8; ++j) v[j] = 0;
        }
        uint4 pk;
        pk.x = (unsigned)v[0] | ((unsigned)v[1] << 16);
        pk.y = (unsigned)v[2] | ((unsigned)v[3] << 16);
        pk.z = (unsigned)v[4] | ((unsigned)v[5] << 16);
        pk.w = (unsigned)v[6] | ((unsigned)v[7] << 16);
        *(uint4*)(Bst + ((kg >> 1) * 4 + (px >> 5)) * 1024
                      + ((px & 31) + 32 * (kg & 1)) * 16) = pk;
    }
}

// ---------------- k2: fused 1x1 conv -> fused2 channel-major ----------------
__global__ __launch_bounds__(256, 4)
void k2_fused(const float* __restrict__ x, const float* __restrict__ ref,
              const float* __restrict__ b_cd, const unsigned short* __restrict__ wsbf,
              unsigned short* __restrict__ ws) {
    __shared__ __align__(16) char B0[32768];
    const int tid = threadIdx.x, l = tid & 63, w = tid >> 6;
    const int b = blockIdx.y, p0 = blockIdx.x * 128;
    const int rl31 = l & 31, kh8 = (l >> 5) * 8;

    #pragma unroll
    for (int it = 0; it < 8; ++it) {        // 2048 tasks: kg(16) x px(128)
        int task = it * 256 + tid;
        int kg = task >> 7, px = task & 127;
        const float* src = (kg < 8) ? x : ref;
        int kbase = (kg & 7) * 8;
        unsigned short v[8];
        #pragma unroll
        for (int j = 0; j < 8; ++j)
            v[j] = f2bf(src[(((size_t)b * 64 + kbase + j) << 14) + p0 + px]);
        uint4 pk;
        pk.x = (unsigned)v[0] | ((unsigned)v[1] << 16);
        pk.y = (unsigned)v[2] | ((unsigned)v[3] << 16);
        pk.z = (unsigned)v[4] | ((unsigned)v[5] << 16);
        pk.w = (unsigned)v[6] | ((unsigned)v[7] << 16);
        *(uint4*)(B0 + ((kg >> 1) * 4 + (px >> 5)) * 1024
                      + ((px & 31) + 32 * (kg & 1)) * 16) = pk;
    }
    __syncthreads();

    f32x16 a0, a1;
    #pragma unroll
    for (int r = 0; r < 16; ++r) { a0[r] = 0.0f; a1[r] = 0.0f; }
    const unsigned short* A0 = wsbf + WS_WCD + rl31 * 128 + kh8;
    #pragma unroll
    for (int s = 0; s < 8; ++s) {
        bf16x8 bf = *(bf16x8*)(B0 + ((s * 4 + w) * 64 + l) * 16);
        bf16x8 x0 = *(const bf16x8*)(A0 + s * 16);
        bf16x8 x1 = *(const bf16x8*)(A0 + 32 * 128 + s * 16);
        a0 = MFMA32(x0, bf, a0);
        a1 = MFMA32(x1, bf, a1);
    }
    unsigned short* f2 = ws + WS_F2 + ((size_t)b << 20);
    int px = p0 + w * 32 + rl31;
    #pragma unroll
    for (int t = 0; t < 2; ++t)
        #pragma unroll
        for (int reg = 0; reg < 16; ++reg) {
            int rl = (reg & 3) + 8 * (reg >> 2) + 4 * (l >> 5);
            int ch = t * 32 + rl;
            float v = (t ? a1[reg] : a0[reg]) + b_cd[ch];
            f2[(ch << 14) + px] = f2bf(v);
        }
}

// ---------------- k3: full-M U-GEMM + pm GEMM + epilogue + out-GEMM ----------
// One block per (h,b). 8 waves: mgroup g = w>>1 (mt = g+4i, i=0..4), ntpair
// np = w&1 (nt = 2np+j). Waves 0-3 also carry the 32x128 pm tile.
// LDS: Bst@0 8K | sidx@8192 9216 | w4h@17408 9216 | mL@26624 4608 |
//      bcL@31232 2304 | uL@33536 16K (f32 pm).  Amod overlay @0 32K (phases).
__global__ __launch_bounds__(512, 2)
void k3_main(const float* __restrict__ x, const float* __restrict__ b_c,
             const float* __restrict__ b_p, const float* __restrict__ b_m,
             const unsigned short* __restrict__ wsbf, float* __restrict__ out) {
    __shared__ __align__(16) char lds[49920];
    char* Bst = lds;
    short* sidx = (short*)(lds + 8192);
    unsigned short* w4h = (unsigned short*)(lds + 17408);
    float* mL = (float*)(lds + 26624);
    float* bcL = (float*)(lds + 31232);
    float* uL = (float*)(lds + 33536);

    const int tid = threadIdx.x, l = tid & 63, w = tid >> 6;
    const int g = w >> 1, np = w & 1;
    // XCD-banded decode: round-robin hw mapping (id%8) -> xcd gets h band of 16
    const int id = blockIdx.x;
    const int hbLin = (id & 7) * 64 + (id >> 3);
    const int b = hbLin & 3, h = hbLin >> 2;
    const unsigned short* f2b = wsbf + WS_F2 + ((size_t)b << 20);

    for (int i = tid; i < 576; i += 512) bcL[i] = b_c[i];

    f32x16 acc[5][2];
    #pragma unroll
    for (int i = 0; i < 5; ++i)
        #pragma unroll
        for (int j = 0; j < 2; ++j)
            #pragma unroll
            for (int r = 0; r < 16; ++r) acc[i][j][r] = 0.0f;
    f32x16 pm;
    #pragma unroll
    for (int r = 0; r < 16; ++r) pm[r] = 0.0f;

    // ---- U-GEMM + pm GEMM: 18 k-chunks, B staged once per (h,b) ----
    #pragma unroll 1
    for (int chunk = 0; chunk < 18; ++chunk) {
        __syncthreads();
        stage_B<512>(Bst, f2b, h, chunk, tid);
        __syncthreads();
        #pragma unroll
        for (int s = 0; s < 2; ++s) {
            const int ks = chunk * 2 + s;
            bf16x8 bf0 = *(bf16x8*)(Bst + ((s * 4 + 2 * np) * 64 + l) * 16);
            bf16x8 bf1 = *(bf16x8*)(Bst + ((s * 4 + 2 * np + 1) * 64 + l) * 16);
            #pragma unroll
            for (int i = 0; i < 5; ++i) {   // A direct from global (L2-resident)
                bf16x8 af = *(const bf16x8*)(wsbf + WS_AC
                                + ((((g + 4 * i) * 36 + ks) * 64 + l) << 3));
                acc[i][0] = MFMA32(af, bf0, acc[i][0]);
                acc[i][1] = MFMA32(af, bf1, acc[i][1]);
            }
            if (w < 4) {
                bf16x8 apm = *(const bf16x8*)(wsbf + WS_APM + ((ks * 64 + l) << 3));
                pm = MFMA32(apm, (g & 1) ? bf1 : bf0, pm);
            }
        }
    }

    // ---- pm tiles -> uL (f32). waves 0-3 cover nt {0,2,1,3} ----
    if (w < 4) {
        int pxp = (2 * np + (g & 1)) * 32 + (l & 31);
        #pragma unroll
        for (int reg = 0; reg < 16; ++reg) {
            int rl = (reg & 3) + 8 * (reg >> 2) + 4 * (l >> 5);
            uL[rl * 128 + pxp] = pm[reg];
        }
    }
    __syncthreads();

    // ---- tables from uL (fp32 math, bias added here) ----
    #pragma unroll 1
    for (int i = tid; i < 1152; i += 512) {
        int n = i >> 7, px = i & 127;
        float offr = uL[n * 128 + px] + b_p[n];
        float offc = uL[(9 + n) * 128 + px] + b_p[9 + n];
        float mraw = uL[(18 + n) * 128 + px] + b_m[n];
        int nr = n / 3, nc = n - nr * 3;
        float pr = (float)(h + nr) + offr;
        float pc = (float)(px + nc) + offc;
        float flr = floorf(pr), flc = floorf(pc);
        float qltr = fminf(fmaxf(flr, 0.0f), 129.0f);
        float qrbr = fminf(fmaxf(flr + 1.0f, 0.0f), 129.0f);
        float qltc = fminf(fmaxf(flc, 0.0f), 129.0f);
        float qrbc = fminf(fmaxf(flc + 1.0f, 0.0f), 129.0f);
        float prc = fminf(fmaxf(pr, 0.0f), 129.0f);
        float pcc = fminf(fmaxf(pc, 0.0f), 129.0f);
        float wltr = 1.0f + qltr - prc, wrbr = 1.0f - (qrbr - prc);
        float wltc = 1.0f + qltc - pcc, wrbc = 1.0f - (qrbc - pcc);
        int iltr = (int)qltr, irbr = (int)qrbr, iltc = (int)qltc, irbc = (int)qrbc;
        bool vlt_r = (iltr >= 1) && (iltr <= 128), vrb_r = (irbr >= 1) && (irbr <= 128);
        bool vlt_c = (iltc >= 1) && (iltc <= 128), vrb_c = (irbc >= 1) && (irbc <= 128);
        short4 s4; float4 f4;
        s4.x = (vlt_r && vlt_c) ? (short)(((iltr - 1) << 7) + (iltc - 1)) : (short)0;
        f4.x = (vlt_r && vlt_c) ? wltr * wltc : 0.0f;
        s4.y = (vrb_r && vrb_c) ? (short)(((irbr - 1) << 7) + (irbc - 1)) : (short)0;
        f4.y = (vrb_r && vrb_c) ? wrbr * wrbc : 0.0f;
        s4.z = (vlt_r && vrb_c) ? (short)(((iltr - 1) << 7) + (irbc - 1)) : (short)0;
        f4.z = (vlt_r && vrb_c) ? wltr * wrbc : 0.0f;
        s4.w = (vrb_r && vlt_c) ? (short)(((irbr - 1) << 7) + (iltc - 1)) : (short)0;
        f4.w = (vrb_r && vlt_c) ? wrbr * wltc : 0.0f;
        ((short4*)sidx)[px * 9 + n] = s4;
        int wb = (px * 9 + n) * 4;
        w4h[wb + 0] = __half_as_ushort(__float2half(f4.x));
        w4h[wb + 1] = __half_as_ushort(__float2half(f4.y));
        w4h[wb + 2] = __half_as_ushort(__float2half(f4.z));
        w4h[wb + 3] = __half_as_ushort(__float2half(f4.w));
        mL[n * 128 + px] = fast_sigmoid(mraw);
    }
    __syncthreads();

    // ---- epilogue: tanh + bilinear sample + modulate (in regs) ----
    const float* xb = x + (((size_t)b * 64) << 14);
    #pragma unroll
    for (int i = 0; i < 5; ++i) {
        const int rowbase = (g + 4 * i) * 32;
        #pragma unroll
        for (int j = 0; j < 2; ++j) {
            const int pxe = (2 * np + j) * 32 + (l & 31);
            if (rowbase < 576) {
                #pragma unroll
                for (int reg = 0; reg < 16; ++reg) {
                    int rl = (reg & 3) + 8 * (reg >> 2) + 4 * (l >> 5);
                    int row = rowbase + rl;
                    int c = row / 9, n = row - c * 9;
                    float uv = acc[i][j][reg] + bcL[row];
                    float t = fast_tanh(uv);
                    short4 s4 = ((short4*)sidx)[pxe * 9 + n];
                    int wb = (pxe * 9 + n) * 4;
                    float w0 = __half2float(__ushort_as_half(w4h[wb + 0]));
                    float w1 = __half2float(__ushort_as_half(w4h[wb + 1]));
                    float w2 = __half2float(__ushort_as_half(w4h[wb + 2]));
                    float w3 = __half2float(__ushort_as_half(w4h[wb + 3]));
                    const float* xp = xb + ((size_t)c << 14);
                    float samp = w0 * xp[s4.x] + w1 * xp[s4.y] + w2 * xp[s4.z] + w3 * xp[s4.w];
                    acc[i][j][reg] = mL[n * 128 + pxe] * (samp + t);
                }
            } else {
                #pragma unroll
                for (int reg = 0; reg < 16; ++reg) acc[i][j][reg] = 0.0f;
            }
        }
    }

    // ---- 5-phase scatter + out-GEMM (oa in regs; NO atomics) ----
    const int ocT = w >> 2, nT2 = w & 3;
    f32x16 oa;
    #pragma unroll
    for (int r = 0; r < 16; ++r) oa[r] = 0.0f;
    #pragma unroll                          // MUST fully unroll: acc[p] static index
    for (int p = 0; p < 5; ++p) {
        __syncthreads();                    // prev phase reads done / tables dead
        #pragma unroll
        for (int j = 0; j < 2; ++j) {
            int nt = 2 * np + j;
            #pragma unroll
            for (int reg = 0; reg < 16; ++reg) {
                int rl = (reg & 3) + 8 * (reg >> 2) + 4 * (l >> 5);
                int k = g * 32 + rl;        // phase-local row: mt g+4p -> slot g
                *(unsigned short*)(lds + ((k >> 4) * 4 + nt) * 1024
                                       + ((l & 31) + 32 * ((k >> 3) & 1)) * 16 + (k & 7) * 2)
                    = f2bf(acc[p][j][reg]);
            }
        }
        __syncthreads();
        #pragma unroll
        for (int ks8 = 0; ks8 < 8; ++ks8) {
            bf16x8 af = *(const bf16x8*)(wsbf + WS_ACONV
                            + (((ocT * 40 + p * 8 + ks8) * 64 + l) << 3));
            bf16x8 bf = *(bf16x8*)(lds + (ks8 * 4 + nT2) * 1024 + l * 16);
            oa = MFMA32(af, bf, oa);
        }
    }
    float* ob = out + (((size_t)b * 64) << 14) + h * 128 + nT2 * 32 + (l & 31);
    #pragma unroll
    for (int reg = 0; reg < 16; ++reg) {
        int rl = (reg & 3) + 8 * (reg >> 2) + 4 * (l >> 5);
        int oc = ocT * 32 + rl;
        ob[(size_t)oc << 14] = oa[reg];     // plain store: each elem written once
    }
}

extern "C" void kernel_launch(void* const* d_in, const int* in_sizes, int n_in,
                              void* d_out, int out_size, void* d_ws, size_t ws_size,
                              hipStream_t stream) {
    const float* x      = (const float*)d_in[0];
    const float* ref    = (const float*)d_in[1];
    const float* w_cd   = (const float*)d_in[2];
    const float* b_cd   = (const float*)d_in[3];
    const float* w_p    = (const float*)d_in[4];
    const float* b_p    = (const float*)d_in[5];
    const float* w_m    = (const float*)d_in[6];
    const float* b_m    = (const float*)d_in[7];
    const float* w_c    = (const float*)d_in[8];
    const float* b_c    = (const float*)d_in[9];
    const float* w_conv = (const float*)d_in[10];
    float* out = (float*)d_out;
    unsigned short* wsbf = (unsigned short*)d_ws;

    hipLaunchKernelGGL(prep_kernel, dim3(1704), dim3(256), 0, stream,
                       w_c, w_p, w_m, w_conv, w_cd, wsbf);
    hipLaunchKernelGGL(k2_fused, dim3(128, 4), dim3(256), 0, stream,
                       x, ref, b_cd, wsbf, wsbf);
    hipLaunchKernelGGL(k3_main, dim3(512), dim3(512), 0, stream,
                       x, b_c, b_p, b_m, wsbf, out);
}

// Round 2
// 398.078 us; speedup vs baseline: 2.4965x; 2.4965x over previous
//
#include <hip/hip_runtime.h>
#include <hip/hip_fp16.h>

// ColorDeformConv2d — round 6: single block per (h,b), 5 serial m-passes,
// acc0/acc1 only (32 VGPR) -> no spill. Atomic-free out-GEMM (oa carried in
// regs across passes). pm GEMM fused into pass 0. Tables built once.
// fused2 repacked [b][cg=ch/8][pix][8ch] so B-staging is 1x16B load + 1x16B
// LDS store per task (coalesced), instead of 8 strided u16 loads.
//
// ws (u16 elems): A_c[20mt][36ks][64l][8] @0 (368640), A_pm @368640 (18432),
// A_conv[2][40][64][8] @387072 (40960), Wcd row-major @428032 (8192),
// fused2 @436224 (4*64*16384, cg-interleaved). Total 9.3 MB.
//
// k3 LDS (66304 B, 2 blocks/CU):
//   Bst@0 8K | Amod@8192 32K (uL f32 overlays first 16K, dead after tables) |
//   sidx@40960 9216 | w4h@50176 9216 | mL@59392 4608 | bcL@64000 2304

typedef __attribute__((ext_vector_type(8))) __bf16 bf16x8;
typedef __attribute__((ext_vector_type(16))) float f32x16;
#define MFMA32(a, b, c) __builtin_amdgcn_mfma_f32_32x32x16_bf16((a), (b), (c), 0, 0, 0)

#define WS_AC    0
#define WS_APM   368640
#define WS_ACONV 387072
#define WS_WCD   428032
#define WS_F2    436224

__device__ __forceinline__ unsigned short f2bf(float f) {
    unsigned u = __float_as_uint(f);
    return (unsigned short)((u + 0x7FFFu + ((u >> 16) & 1u)) >> 16);   // RNE
}
__device__ __forceinline__ float fast_rcp(float x) {
#if __has_builtin(__builtin_amdgcn_rcpf)
    return __builtin_amdgcn_rcpf(x);
#else
    return 1.0f / x;
#endif
}
__device__ __forceinline__ float fast_tanh(float x) {
    float t = __expf(2.0f * x);
    return 1.0f - 2.0f * fast_rcp(t + 1.0f);
}
__device__ __forceinline__ float fast_sigmoid(float x) {
    return fast_rcp(1.0f + __expf(-x));
}

// ---------------- prep: weight repack to frag-order bf16 (unchanged) --------
__global__ void prep_kernel(const float* __restrict__ w_c, const float* __restrict__ w_p,
                            const float* __restrict__ w_m, const float* __restrict__ w_conv,
                            const float* __restrict__ w_cd, unsigned short* __restrict__ ws) {
    int i = blockIdx.x * 256 + threadIdx.x;
    if (i >= 436224) return;
    float val;
    if (i < WS_APM) {                       // A_c: row=gmt*32+(l&31), k'=ks*16+(l>>5)*8+j
        int t = i, j = t & 7, l = (t >> 3) & 63, r = t >> 9, ks = r % 36, gmt = r / 36;
        int row = gmt * 32 + (l & 31);
        int kp = ks * 16 + (l >> 5) * 8 + j, tap = kp >> 6, ci = kp & 63;
        val = (row < 576) ? w_c[row * 576 + ci * 9 + tap] : 0.0f;
    } else if (i < WS_ACONV) {              // A_pm: rows 0-17 w_p, 18-26 w_m
        int t = i - WS_APM, j = t & 7, l = (t >> 3) & 63, ks = t >> 9;
        int row = l & 31;
        int kp = ks * 16 + (l >> 5) * 8 + j, tap = kp >> 6, ci = kp & 63;
        val = (row < 18) ? w_p[row * 576 + ci * 9 + tap]
            : (row < 27) ? w_m[(row - 18) * 576 + ci * 9 + tap] : 0.0f;
    } else if (i < WS_WCD) {                // A_conv: k = U-row (natural order)
        int t = i - WS_ACONV, j = t & 7, l = (t >> 3) & 63, r = t >> 9;
        int gks = r % 40, ocT = r / 40;
        int oc = ocT * 32 + (l & 31);
        int krow = gks * 16 + (l >> 5) * 8 + j;
        val = (krow < 576) ? w_conv[oc * 576 + krow] : 0.0f;
    } else {                                // Wcd row-major [64][128]
        val = w_cd[i - WS_WCD];
    }
    ws[i] = f2bf(val);
}

// ------ im2col B-stage from cg-interleaved fused2: 1 task/thread, 16B each --
__device__ __forceinline__ void stage_B(char* Bst, const unsigned short* f2b,
                                        int h, int chunk, int tid) {
    int tap = chunk >> 1;
    int dh = tap / 3 - 1, dw = tap % 3 - 1;
    int hs = h + dh;
    int kg = tid >> 7, px = tid & 127;      // 512 tasks: kg(4) x px(128)
    int cg = (chunk & 1) * 4 + kg;          // channels cg*8 .. cg*8+7
    int wsrc = px + dw;
    uint4 pk = {0u, 0u, 0u, 0u};
    if (((unsigned)hs < 128u) && ((unsigned)wsrc < 128u))
        pk = *(const uint4*)(f2b + (((size_t)cg << 14) + (hs << 7) + wsrc) * 8);
    *(uint4*)(Bst + ((kg >> 1) * 4 + (px >> 5)) * 1024
                  + ((px & 31) + 32 * (kg & 1)) * 16) = pk;
}

// ---------------- k2: fused 1x1 conv -> fused2 cg-interleaved ----------------
__global__ __launch_bounds__(256, 4)
void k2_fused(const float* __restrict__ x, const float* __restrict__ ref,
              const float* __restrict__ b_cd, const unsigned short* __restrict__ wsbf,
              unsigned short* __restrict__ ws) {
    __shared__ __align__(16) char B0[32768];
    const int tid = threadIdx.x, l = tid & 63, w = tid >> 6;
    const int b = blockIdx.y, p0 = blockIdx.x * 128;
    const int rl31 = l & 31, kh8 = (l >> 5) * 8;

    #pragma unroll
    for (int it = 0; it < 8; ++it) {        // 2048 tasks: kg(16) x px(128)
        int task = it * 256 + tid;
        int kg = task >> 7, px = task & 127;
        const float* src = (kg < 8) ? x : ref;
        int kbase = (kg & 7) * 8;
        unsigned short v[8];
        #pragma unroll
        for (int j = 0; j < 8; ++j)
            v[j] = f2bf(src[(((size_t)b * 64 + kbase + j) << 14) + p0 + px]);
        uint4 pk;
        pk.x = (unsigned)v[0] | ((unsigned)v[1] << 16);
        pk.y = (unsigned)v[2] | ((unsigned)v[3] << 16);
        pk.z = (unsigned)v[4] | ((unsigned)v[5] << 16);
        pk.w = (unsigned)v[6] | ((unsigned)v[7] << 16);
        *(uint4*)(B0 + ((kg >> 1) * 4 + (px >> 5)) * 1024
                      + ((px & 31) + 32 * (kg & 1)) * 16) = pk;
    }
    __syncthreads();

    f32x16 a0, a1;
    #pragma unroll
    for (int r = 0; r < 16; ++r) { a0[r] = 0.0f; a1[r] = 0.0f; }
    const unsigned short* A0 = wsbf + WS_WCD + rl31 * 128 + kh8;
    #pragma unroll
    for (int s = 0; s < 8; ++s) {
        bf16x8 bf = *(bf16x8*)(B0 + ((s * 4 + w) * 64 + l) * 16);
        bf16x8 x0 = *(const bf16x8*)(A0 + s * 16);
        bf16x8 x1 = *(const bf16x8*)(A0 + 32 * 128 + s * 16);
        a0 = MFMA32(x0, bf, a0);
        a1 = MFMA32(x1, bf, a1);
    }
    // store cg-interleaved: f2[(cg*16384 + px)*8 + (ch&7)], cg = ch>>3
    // reg = q*4 + r2 -> rl = r2 + 8q + 4h (h = l>>5), ch = t*32 + 8q + 4h + r2
    unsigned short* f2 = ws + WS_F2 + ((size_t)b << 20);
    int px = p0 + w * 32 + rl31;
    int h4 = (l >> 5) * 4;
    #pragma unroll
    for (int t = 0; t < 2; ++t)
        #pragma unroll
        for (int q = 0; q < 4; ++q) {
            ushort4 st;
            float v0 = (t ? a1[q * 4 + 0] : a0[q * 4 + 0]) + b_cd[t * 32 + 8 * q + h4 + 0];
            float v1 = (t ? a1[q * 4 + 1] : a0[q * 4 + 1]) + b_cd[t * 32 + 8 * q + h4 + 1];
            float v2 = (t ? a1[q * 4 + 2] : a0[q * 4 + 2]) + b_cd[t * 32 + 8 * q + h4 + 2];
            float v3 = (t ? a1[q * 4 + 3] : a0[q * 4 + 3]) + b_cd[t * 32 + 8 * q + h4 + 3];
            st.x = f2bf(v0); st.y = f2bf(v1); st.z = f2bf(v2); st.w = f2bf(v3);
            *(ushort4*)(f2 + ((size_t)((t * 4 + q) << 14) + px) * 8 + h4) = st;
        }
}

// ---------------- k3: 5 serial m-passes, atomic-free --------------------------
__global__ __launch_bounds__(512, 4)
void k3_main(const float* __restrict__ x, const float* __restrict__ b_c,
             const float* __restrict__ b_p, const float* __restrict__ b_m,
             const unsigned short* __restrict__ wsbf, float* __restrict__ out) {
    __shared__ __align__(16) char lds[66304];
    char* Bst = lds;
    char* Amod = lds + 8192;
    float* uL = (float*)(lds + 8192);       // overlays Amod; dead after tables
    short* sidx = (short*)(lds + 40960);
    unsigned short* w4h = (unsigned short*)(lds + 50176);
    float* mL = (float*)(lds + 59392);
    float* bcL = (float*)(lds + 64000);

    const int tid = threadIdx.x, l = tid & 63, w = tid >> 6;
    const int g = w >> 1, np = w & 1;
    // XCD-banded decode: xcd = id&7 owns h band [xcd*16, xcd*16+16) x all b
    const int id = blockIdx.x;
    const int hbLin = (id & 7) * 64 + (id >> 3);
    const int b = hbLin & 3, h = hbLin >> 2;
    const unsigned short* f2b = wsbf + WS_F2 + ((size_t)b << 20);

    for (int i = tid; i < 576; i += 512) bcL[i] = b_c[i];

    const int ocT = w >> 2, nT2 = w & 3;
    f32x16 oa;
    #pragma unroll
    for (int r = 0; r < 16; ++r) oa[r] = 0.0f;
    const float* xb = x + (((size_t)b * 64) << 14);

    #pragma unroll 1
    for (int p = 0; p < 5; ++p) {
        const int mt = p * 4 + g;           // this wave's m-tile (rows mt*32..+31)
        f32x16 acc0, acc1, pm;
        #pragma unroll
        for (int r = 0; r < 16; ++r) { acc0[r] = 0.0f; acc1[r] = 0.0f; pm[r] = 0.0f; }

        // ---- U-GEMM k-loop (pm fused in pass 0, waves 0-3) ----
        #pragma unroll 1
        for (int chunk = 0; chunk < 18; ++chunk) {
            __syncthreads();
            stage_B(Bst, f2b, h, chunk, tid);
            __syncthreads();
            #pragma unroll
            for (int s = 0; s < 2; ++s) {
                const int ks = chunk * 2 + s;
                bf16x8 bf0 = *(bf16x8*)(Bst + ((s * 4 + 2 * np) * 64 + l) * 16);
                bf16x8 bf1 = *(bf16x8*)(Bst + ((s * 4 + 2 * np + 1) * 64 + l) * 16);
                bf16x8 af = *(const bf16x8*)(wsbf + WS_AC
                                + (((mt * 36 + ks) * 64 + l) << 3));
                acc0 = MFMA32(af, bf0, acc0);
                acc1 = MFMA32(af, bf1, acc1);
                if (p == 0 && w < 4) {
                    bf16x8 apm = *(const bf16x8*)(wsbf + WS_APM + ((ks * 64 + l) << 3));
                    pm = MFMA32(apm, (g & 1) ? bf1 : bf0, pm);
                }
            }
        }

        if (p == 0) {
            // pm tiles -> uL (f32); waves 0-3 cover nt {0,2,1,3}
            if (w < 4) {
                int pxp = (2 * np + (g & 1)) * 32 + (l & 31);
                #pragma unroll
                for (int reg = 0; reg < 16; ++reg) {
                    int rl = (reg & 3) + 8 * (reg >> 2) + 4 * (l >> 5);
                    uL[rl * 128 + pxp] = pm[reg];
                }
            }
            __syncthreads();
            // ---- tables from uL (built once per block) ----
            #pragma unroll 1
            for (int i = tid; i < 1152; i += 512) {
                int n = i >> 7, px = i & 127;
                float offr = uL[n * 128 + px] + b_p[n];
                float offc = uL[(9 + n) * 128 + px] + b_p[9 + n];
                float mraw = uL[(18 + n) * 128 + px] + b_m[n];
                int nr = n / 3, nc = n - nr * 3;
                float pr = (float)(h + nr) + offr;
                float pc = (float)(px + nc) + offc;
                float flr = floorf(pr), flc = floorf(pc);
                float qltr = fminf(fmaxf(flr, 0.0f), 129.0f);
                float qrbr = fminf(fmaxf(flr + 1.0f, 0.0f), 129.0f);
                float qltc = fminf(fmaxf(flc, 0.0f), 129.0f);
                float qrbc = fminf(fmaxf(flc + 1.0f, 0.0f), 129.0f);
                float prc = fminf(fmaxf(pr, 0.0f), 129.0f);
                float pcc = fminf(fmaxf(pc, 0.0f), 129.0f);
                float wltr = 1.0f + qltr - prc, wrbr = 1.0f - (qrbr - prc);
                float wltc = 1.0f + qltc - pcc, wrbc = 1.0f - (qrbc - pcc);
                int iltr = (int)qltr, irbr = (int)qrbr, iltc = (int)qltc, irbc = (int)qrbc;
                bool vlt_r = (iltr >= 1) && (iltr <= 128), vrb_r = (irbr >= 1) && (irbr <= 128);
                bool vlt_c = (iltc >= 1) && (iltc <= 128), vrb_c = (irbc >= 1) && (irbc <= 128);
                short4 s4; float4 f4;
                s4.x = (vlt_r && vlt_c) ? (short)(((iltr - 1) << 7) + (iltc - 1)) : (short)0;
                f4.x = (vlt_r && vlt_c) ? wltr * wltc : 0.0f;
                s4.y = (vrb_r && vrb_c) ? (short)(((irbr - 1) << 7) + (irbc - 1)) : (short)0;
                f4.y = (vrb_r && vrb_c) ? wrbr * wrbc : 0.0f;
                s4.z = (vlt_r && vrb_c) ? (short)(((iltr - 1) << 7) + (irbc - 1)) : (short)0;
                f4.z = (vlt_r && vrb_c) ? wltr * wrbc : 0.0f;
                s4.w = (vrb_r && vlt_c) ? (short)(((irbr - 1) << 7) + (iltc - 1)) : (short)0;
                f4.w = (vrb_r && vlt_c) ? wrbr * wltc : 0.0f;
                ((short4*)sidx)[px * 9 + n] = s4;
                int wb = (px * 9 + n) * 4;
                w4h[wb + 0] = __half_as_ushort(__float2half(f4.x));
                w4h[wb + 1] = __half_as_ushort(__float2half(f4.y));
                w4h[wb + 2] = __half_as_ushort(__float2half(f4.z));
                w4h[wb + 3] = __half_as_ushort(__float2half(f4.w));
                mL[n * 128 + px] = fast_sigmoid(mraw);
            }
            __syncthreads();
        }

        // ---- epilogue: tanh + bilinear sample + modulate (in regs) ----
        const int rowbase = mt * 32;
        auto epi = [&](f32x16& a, int j) {
            const int pxe = (2 * np + j) * 32 + (l & 31);
            if (rowbase < 576) {
                #pragma unroll
                for (int reg = 0; reg < 16; ++reg) {
                    int rl = (reg & 3) + 8 * (reg >> 2) + 4 * (l >> 5);
                    int row = rowbase + rl;
                    int c = row / 9, n = row - c * 9;
                    float uv = a[reg] + bcL[row];
                    float t = fast_tanh(uv);
                    short4 s4 = ((short4*)sidx)[pxe * 9 + n];
                    int wb = (pxe * 9 + n) * 4;
                    float w0 = __half2float(__ushort_as_half(w4h[wb + 0]));
                    float w1 = __half2float(__ushort_as_half(w4h[wb + 1]));
                    float w2 = __half2float(__ushort_as_half(w4h[wb + 2]));
                    float w3 = __half2float(__ushort_as_half(w4h[wb + 3]));
                    const float* xp = xb + ((size_t)c << 14);
                    float samp = w0 * xp[s4.x] + w1 * xp[s4.y] + w2 * xp[s4.z] + w3 * xp[s4.w];
                    a[reg] = mL[n * 128 + pxe] * (samp + t);
                }
            } else {
                #pragma unroll
                for (int reg = 0; reg < 16; ++reg) a[reg] = 0.0f;
            }
        };
        epi(acc0, 0);
        epi(acc1, 1);

        __syncthreads();                    // prev out-GEMM Amod reads / uL reads done
        // ---- scatter this pass's 128xN rows to Amod B-frag layout ----
        auto scat = [&](const f32x16& a, int j) {
            int nt = 2 * np + j;
            #pragma unroll
            for (int reg = 0; reg < 16; ++reg) {
                int rl = (reg & 3) + 8 * (reg >> 2) + 4 * (l >> 5);
                int k = g * 32 + rl;        // pass-local row
                *(unsigned short*)(Amod + ((k >> 4) * 4 + nt) * 1024
                                        + ((l & 31) + 32 * ((k >> 3) & 1)) * 16 + (k & 7) * 2)
                    = f2bf(a[reg]);
            }
        };
        scat(acc0, 0);
        scat(acc1, 1);
        __syncthreads();
        // ---- out-GEMM accumulate: oa += w_conv_chunk @ Amod ----
        #pragma unroll
        for (int ks8 = 0; ks8 < 8; ++ks8) {
            bf16x8 af = *(const bf16x8*)(wsbf + WS_ACONV
                            + (((ocT * 40 + p * 8 + ks8) * 64 + l) << 3));
            bf16x8 bf = *(bf16x8*)(Amod + (ks8 * 4 + nT2) * 1024 + l * 16);
            oa = MFMA32(af, bf, oa);
        }
    }

    // ---- final store: each out element written exactly once ----
    float* ob = out + (((size_t)b * 64) << 14) + (h << 7) + nT2 * 32 + (l & 31);
    #pragma unroll
    for (int reg = 0; reg < 16; ++reg) {
        int rl = (reg & 3) + 8 * (reg >> 2) + 4 * (l >> 5);
        int oc = ocT * 32 + rl;
        ob[(size_t)oc << 14] = oa[reg];
    }
}

extern "C" void kernel_launch(void* const* d_in, const int* in_sizes, int n_in,
                              void* d_out, int out_size, void* d_ws, size_t ws_size,
                              hipStream_t stream) {
    const float* x      = (const float*)d_in[0];
    const float* ref    = (const float*)d_in[1];
    const float* w_cd   = (const float*)d_in[2];
    const float* b_cd   = (const float*)d_in[3];
    const float* w_p    = (const float*)d_in[4];
    const float* b_p    = (const float*)d_in[5];
    const float* w_m    = (const float*)d_in[6];
    const float* b_m    = (const float*)d_in[7];
    const float* w_c    = (const float*)d_in[8];
    const float* b_c    = (const float*)d_in[9];
    const float* w_conv = (const float*)d_in[10];
    float* out = (float*)d_out;
    unsigned short* wsbf = (unsigned short*)d_ws;

    hipLaunchKernelGGL(prep_kernel, dim3(1704), dim3(256), 0, stream,
                       w_c, w_p, w_m, w_conv, w_cd, wsbf);
    hipLaunchKernelGGL(k2_fused, dim3(128, 4), dim3(256), 0, stream,
                       x, ref, b_cd, wsbf, wsbf);
    hipLaunchKernelGGL(k3_main, dim3(512), dim3(512), 0, stream,
                       x, b_c, b_p, b_m, wsbf, out);
}

// Round 3
// 393.044 us; speedup vs baseline: 2.5284x; 1.0128x over previous
//
#include <hip/hip_runtime.h>
#include <hip/hip_fp16.h>

// ColorDeformConv2d — round 7: fit the 128-reg budget for real + hide staging.
// vs r6: (1) pm GEMM moved to a dedicated pre-phase (waves 0-3), so the hot
// 5-pass loop carries only acc0/acc1/oa = 48 AGPRs -> 80 arch VGPRs free;
// (2) epilogue gather clustering bounded by sched_barrier(0) every 4 regs;
// (3) Bst double-buffered: load(next) -> MFMA(cur) -> ds_write(next) -> one
// barrier per chunk (was 2), L2 latency hidden under MFMA.
//
// ws (u16 elems): A_c[20mt][36ks][64l][8] @0 (368640), A_pm @368640 (18432),
// A_conv[2][40][64][8] @387072 (40960), Wcd row-major @428032 (8192),
// fused2 @436224 (4*64*16384, cg-interleaved). Total 9.3 MB.
//
// k3 LDS (74496 B, 2 blocks/CU):
//   Bst0@0 8K | Bst1@8192 8K | Amod@16384 32K (uL f32 overlays first 16K,
//   dead after tables) | sidx@49152 9216 | w4h@58368 9216 | mL@67584 4608 |
//   bcL@72192 2304

typedef __attribute__((ext_vector_type(8))) __bf16 bf16x8;
typedef __attribute__((ext_vector_type(16))) float f32x16;
#define MFMA32(a, b, c) __builtin_amdgcn_mfma_f32_32x32x16_bf16((a), (b), (c), 0, 0, 0)

#define WS_AC    0
#define WS_APM   368640
#define WS_ACONV 387072
#define WS_WCD   428032
#define WS_F2    436224

__device__ __forceinline__ unsigned short f2bf(float f) {
    unsigned u = __float_as_uint(f);
    return (unsigned short)((u + 0x7FFFu + ((u >> 16) & 1u)) >> 16);   // RNE
}
__device__ __forceinline__ float fast_rcp(float x) {
#if __has_builtin(__builtin_amdgcn_rcpf)
    return __builtin_amdgcn_rcpf(x);
#else
    return 1.0f / x;
#endif
}
__device__ __forceinline__ float fast_tanh(float x) {
    float t = __expf(2.0f * x);
    return 1.0f - 2.0f * fast_rcp(t + 1.0f);
}
__device__ __forceinline__ float fast_sigmoid(float x) {
    return fast_rcp(1.0f + __expf(-x));
}

// ---------------- prep: weight repack to frag-order bf16 (unchanged) --------
__global__ void prep_kernel(const float* __restrict__ w_c, const float* __restrict__ w_p,
                            const float* __restrict__ w_m, const float* __restrict__ w_conv,
                            const float* __restrict__ w_cd, unsigned short* __restrict__ ws) {
    int i = blockIdx.x * 256 + threadIdx.x;
    if (i >= 436224) return;
    float val;
    if (i < WS_APM) {                       // A_c: row=gmt*32+(l&31), k'=ks*16+(l>>5)*8+j
        int t = i, j = t & 7, l = (t >> 3) & 63, r = t >> 9, ks = r % 36, gmt = r / 36;
        int row = gmt * 32 + (l & 31);
        int kp = ks * 16 + (l >> 5) * 8 + j, tap = kp >> 6, ci = kp & 63;
        val = (row < 576) ? w_c[row * 576 + ci * 9 + tap] : 0.0f;
    } else if (i < WS_ACONV) {              // A_pm: rows 0-17 w_p, 18-26 w_m
        int t = i - WS_APM, j = t & 7, l = (t >> 3) & 63, ks = t >> 9;
        int row = l & 31;
        int kp = ks * 16 + (l >> 5) * 8 + j, tap = kp >> 6, ci = kp & 63;
        val = (row < 18) ? w_p[row * 576 + ci * 9 + tap]
            : (row < 27) ? w_m[(row - 18) * 576 + ci * 9 + tap] : 0.0f;
    } else if (i < WS_WCD) {                // A_conv: k = U-row (natural order)
        int t = i - WS_ACONV, j = t & 7, l = (t >> 3) & 63, r = t >> 9;
        int gks = r % 40, ocT = r / 40;
        int oc = ocT * 32 + (l & 31);
        int krow = gks * 16 + (l >> 5) * 8 + j;
        val = (krow < 576) ? w_conv[oc * 576 + krow] : 0.0f;
    } else {                                // Wcd row-major [64][128]
        val = w_cd[i - WS_WCD];
    }
    ws[i] = f2bf(val);
}

// ------ im2col B-stage, split into load (global->reg) and write (reg->LDS) --
__device__ __forceinline__ uint4 stage_load(const unsigned short* f2b,
                                            int h, int chunk, int tid) {
    int tap = chunk >> 1;
    int dh = tap / 3 - 1, dw = tap % 3 - 1;
    int hs = h + dh;
    int kg = tid >> 7, px = tid & 127;      // 512 tasks: kg(4) x px(128)
    int cg = (chunk & 1) * 4 + kg;          // channels cg*8 .. cg*8+7
    int wsrc = px + dw;
    uint4 pk = {0u, 0u, 0u, 0u};
    if (((unsigned)hs < 128u) && ((unsigned)wsrc < 128u))
        pk = *(const uint4*)(f2b + (((size_t)cg << 14) + (hs << 7) + wsrc) * 8);
    return pk;
}
__device__ __forceinline__ void stage_write(char* Bst, uint4 pk, int tid) {
    int kg = tid >> 7, px = tid & 127;
    *(uint4*)(Bst + ((kg >> 1) * 4 + (px >> 5)) * 1024
                  + ((px & 31) + 32 * (kg & 1)) * 16) = pk;
}

// ---------------- k2: fused 1x1 conv -> fused2 cg-interleaved (unchanged) ----
__global__ __launch_bounds__(256, 4)
void k2_fused(const float* __restrict__ x, const float* __restrict__ ref,
              const float* __restrict__ b_cd, const unsigned short* __restrict__ wsbf,
              unsigned short* __restrict__ ws) {
    __shared__ __align__(16) char B0[32768];
    const int tid = threadIdx.x, l = tid & 63, w = tid >> 6;
    const int b = blockIdx.y, p0 = blockIdx.x * 128;
    const int rl31 = l & 31, kh8 = (l >> 5) * 8;

    #pragma unroll
    for (int it = 0; it < 8; ++it) {        // 2048 tasks: kg(16) x px(128)
        int task = it * 256 + tid;
        int kg = task >> 7, px = task & 127;
        const float* src = (kg < 8) ? x : ref;
        int kbase = (kg & 7) * 8;
        unsigned short v[8];
        #pragma unroll
        for (int j = 0; j < 8; ++j)
            v[j] = f2bf(src[(((size_t)b * 64 + kbase + j) << 14) + p0 + px]);
        uint4 pk;
        pk.x = (unsigned)v[0] | ((unsigned)v[1] << 16);
        pk.y = (unsigned)v[2] | ((unsigned)v[3] << 16);
        pk.z = (unsigned)v[4] | ((unsigned)v[5] << 16);
        pk.w = (unsigned)v[6] | ((unsigned)v[7] << 16);
        *(uint4*)(B0 + ((kg >> 1) * 4 + (px >> 5)) * 1024
                      + ((px & 31) + 32 * (kg & 1)) * 16) = pk;
    }
    __syncthreads();

    f32x16 a0, a1;
    #pragma unroll
    for (int r = 0; r < 16; ++r) { a0[r] = 0.0f; a1[r] = 0.0f; }
    const unsigned short* A0 = wsbf + WS_WCD + rl31 * 128 + kh8;
    #pragma unroll
    for (int s = 0; s < 8; ++s) {
        bf16x8 bf = *(bf16x8*)(B0 + ((s * 4 + w) * 64 + l) * 16);
        bf16x8 x0 = *(const bf16x8*)(A0 + s * 16);
        bf16x8 x1 = *(const bf16x8*)(A0 + 32 * 128 + s * 16);
        a0 = MFMA32(x0, bf, a0);
        a1 = MFMA32(x1, bf, a1);
    }
    unsigned short* f2 = ws + WS_F2 + ((size_t)b << 20);
    int px = p0 + w * 32 + rl31;
    int h4 = (l >> 5) * 4;
    #pragma unroll
    for (int t = 0; t < 2; ++t)
        #pragma unroll
        for (int q = 0; q < 4; ++q) {
            ushort4 st;
            float v0 = (t ? a1[q * 4 + 0] : a0[q * 4 + 0]) + b_cd[t * 32 + 8 * q + h4 + 0];
            float v1 = (t ? a1[q * 4 + 1] : a0[q * 4 + 1]) + b_cd[t * 32 + 8 * q + h4 + 1];
            float v2 = (t ? a1[q * 4 + 2] : a0[q * 4 + 2]) + b_cd[t * 32 + 8 * q + h4 + 2];
            float v3 = (t ? a1[q * 4 + 3] : a0[q * 4 + 3]) + b_cd[t * 32 + 8 * q + h4 + 3];
            st.x = f2bf(v0); st.y = f2bf(v1); st.z = f2bf(v2); st.w = f2bf(v3);
            *(ushort4*)(f2 + ((size_t)((t * 4 + q) << 14) + px) * 8 + h4) = st;
        }
}

// ---------------- k3: pm pre-phase + 5 serial m-passes, double-buffered -----
__global__ __launch_bounds__(512, 4)
void k3_main(const float* __restrict__ x, const float* __restrict__ b_c,
             const float* __restrict__ b_p, const float* __restrict__ b_m,
             const unsigned short* __restrict__ wsbf, float* __restrict__ out) {
    __shared__ __align__(16) char lds[74496];
    char* Bst0 = lds;
    char* Bst1 = lds + 8192;
    char* Amod = lds + 16384;
    float* uL = (float*)(lds + 16384);      // overlays Amod; dead after tables
    short* sidx = (short*)(lds + 49152);
    unsigned short* w4h = (unsigned short*)(lds + 58368);
    float* mL = (float*)(lds + 67584);
    float* bcL = (float*)(lds + 72192);

    const int tid = threadIdx.x, l = tid & 63, w = tid >> 6;
    const int g = w >> 1, np = w & 1;
    // XCD-banded decode: xcd = id&7 owns h band [xcd*16, xcd*16+16) x all b
    const int id = blockIdx.x;
    const int hbLin = (id & 7) * 64 + (id >> 3);
    const int b = hbLin & 3, h = hbLin >> 2;
    const unsigned short* f2b = wsbf + WS_F2 + ((size_t)b << 20);

    for (int i = tid; i < 576; i += 512) bcL[i] = b_c[i];

    // ================= pm pre-phase: U_pm[27][128] =================
    {
        f32x16 pm;
        #pragma unroll
        for (int r = 0; r < 16; ++r) pm[r] = 0.0f;
        uint4 pk = stage_load(f2b, h, 0, tid);
        stage_write(Bst0, pk, tid);
        __syncthreads();
        #pragma unroll 2
        for (int chunk = 0; chunk < 18; ++chunk) {
            char* cur = (chunk & 1) ? Bst1 : Bst0;
            char* nxt = (chunk & 1) ? Bst0 : Bst1;
            uint4 pknext;
            if (chunk < 17) pknext = stage_load(f2b, h, chunk + 1, tid);
            if (w < 4) {                    // wave w owns n-tile nt=w
                #pragma unroll
                for (int s = 0; s < 2; ++s) {
                    bf16x8 bf = *(bf16x8*)(cur + ((s * 4 + w) * 64 + l) * 16);
                    bf16x8 apm = *(const bf16x8*)(wsbf + WS_APM
                                    + (((chunk * 2 + s) * 64 + l) << 3));
                    pm = MFMA32(apm, bf, pm);
                }
            }
            if (chunk < 17) stage_write(nxt, pknext, tid);
            __syncthreads();
        }
        if (w < 4) {                        // pm -> uL (f32), nt = w
            int pxp = w * 32 + (l & 31);
            #pragma unroll
            for (int reg = 0; reg < 16; ++reg) {
                int rl = (reg & 3) + 8 * (reg >> 2) + 4 * (l >> 5);
                uL[rl * 128 + pxp] = pm[reg];
            }
        }
        __syncthreads();
    }

    // ================= tables from uL (built once per block) =================
    #pragma unroll 1
    for (int i = tid; i < 1152; i += 512) {
        int n = i >> 7, px = i & 127;
        float offr = uL[n * 128 + px] + b_p[n];
        float offc = uL[(9 + n) * 128 + px] + b_p[9 + n];
        float mraw = uL[(18 + n) * 128 + px] + b_m[n];
        int nr = n / 3, nc = n - nr * 3;
        float pr = (float)(h + nr) + offr;
        float pc = (float)(px + nc) + offc;
        float flr = floorf(pr), flc = floorf(pc);
        float qltr = fminf(fmaxf(flr, 0.0f), 129.0f);
        float qrbr = fminf(fmaxf(flr + 1.0f, 0.0f), 129.0f);
        float qltc = fminf(fmaxf(flc, 0.0f), 129.0f);
        float qrbc = fminf(fmaxf(flc + 1.0f, 0.0f), 129.0f);
        float prc = fminf(fmaxf(pr, 0.0f), 129.0f);
        float pcc = fminf(fmaxf(pc, 0.0f), 129.0f);
        float wltr = 1.0f + qltr - prc, wrbr = 1.0f - (qrbr - prc);
        float wltc = 1.0f + qltc - pcc, wrbc = 1.0f - (qrbc - pcc);
        int iltr = (int)qltr, irbr = (int)qrbr, iltc = (int)qltc, irbc = (int)qrbc;
        bool vlt_r = (iltr >= 1) && (iltr <= 128), vrb_r = (irbr >= 1) && (irbr <= 128);
        bool vlt_c = (iltc >= 1) && (iltc <= 128), vrb_c = (irbc >= 1) && (irbc <= 128);
        short4 s4; float4 f4;
        s4.x = (vlt_r && vlt_c) ? (short)(((iltr - 1) << 7) + (iltc - 1)) : (short)0;
        f4.x = (vlt_r && vlt_c) ? wltr * wltc : 0.0f;
        s4.y = (vrb_r && vrb_c) ? (short)(((irbr - 1) << 7) + (irbc - 1)) : (short)0;
        f4.y = (vrb_r && vrb_c) ? wrbr * wrbc : 0.0f;
        s4.z = (vlt_r && vrb_c) ? (short)(((iltr - 1) << 7) + (irbc - 1)) : (short)0;
        f4.z = (vlt_r && vrb_c) ? wltr * wrbc : 0.0f;
        s4.w = (vrb_r && vlt_c) ? (short)(((irbr - 1) << 7) + (iltc - 1)) : (short)0;
        f4.w = (vrb_r && vlt_c) ? wrbr * wltc : 0.0f;
        ((short4*)sidx)[px * 9 + n] = s4;
        int wb = (px * 9 + n) * 4;
        w4h[wb + 0] = __half_as_ushort(__float2half(f4.x));
        w4h[wb + 1] = __half_as_ushort(__float2half(f4.y));
        w4h[wb + 2] = __half_as_ushort(__float2half(f4.z));
        w4h[wb + 3] = __half_as_ushort(__float2half(f4.w));
        mL[n * 128 + px] = fast_sigmoid(mraw);
    }
    __syncthreads();

    // ================= 5 serial m-passes =================
    const int ocT = w >> 2, nT2 = w & 3;
    f32x16 oa;
    #pragma unroll
    for (int r = 0; r < 16; ++r) oa[r] = 0.0f;
    const float* xb = x + (((size_t)b * 64) << 14);

    #pragma unroll 1
    for (int p = 0; p < 5; ++p) {
        const int mt = p * 4 + g;           // this wave's m-tile (rows mt*32..+31)
        f32x16 acc0, acc1;
        #pragma unroll
        for (int r = 0; r < 16; ++r) { acc0[r] = 0.0f; acc1[r] = 0.0f; }

        // ---- U-GEMM k-loop, double-buffered, 1 barrier/chunk ----
        {
            uint4 pk = stage_load(f2b, h, 0, tid);
            stage_write(Bst0, pk, tid);
            __syncthreads();
        }
        #pragma unroll 2
        for (int chunk = 0; chunk < 18; ++chunk) {
            char* cur = (chunk & 1) ? Bst1 : Bst0;
            char* nxt = (chunk & 1) ? Bst0 : Bst1;
            uint4 pknext;
            if (chunk < 17) pknext = stage_load(f2b, h, chunk + 1, tid);
            #pragma unroll
            for (int s = 0; s < 2; ++s) {
                const int ks = chunk * 2 + s;
                bf16x8 bf0 = *(bf16x8*)(cur + ((s * 4 + 2 * np) * 64 + l) * 16);
                bf16x8 bf1 = *(bf16x8*)(cur + ((s * 4 + 2 * np + 1) * 64 + l) * 16);
                bf16x8 af = *(const bf16x8*)(wsbf + WS_AC
                                + (((mt * 36 + ks) * 64 + l) << 3));
                acc0 = MFMA32(af, bf0, acc0);
                acc1 = MFMA32(af, bf1, acc1);
            }
            if (chunk < 17) stage_write(nxt, pknext, tid);
            __syncthreads();
        }

        // ---- epilogue: tanh + bilinear sample + modulate (in regs) ----
        const int rowbase = mt * 32;
        auto epi = [&](f32x16& a, int j) {
            const int pxe = (2 * np + j) * 32 + (l & 31);
            if (rowbase < 576) {
                #pragma unroll
                for (int reg = 0; reg < 16; ++reg) {
                    int rl = (reg & 3) + 8 * (reg >> 2) + 4 * (l >> 5);
                    int row = rowbase + rl;
                    int c = row / 9, n = row - c * 9;
                    float uv = a[reg] + bcL[row];
                    float t = fast_tanh(uv);
                    short4 s4 = ((short4*)sidx)[pxe * 9 + n];
                    int wb = (pxe * 9 + n) * 4;
                    float w0 = __half2float(__ushort_as_half(w4h[wb + 0]));
                    float w1 = __half2float(__ushort_as_half(w4h[wb + 1]));
                    float w2 = __half2float(__ushort_as_half(w4h[wb + 2]));
                    float w3 = __half2float(__ushort_as_half(w4h[wb + 3]));
                    const float* xp = xb + ((size_t)c << 14);
                    float samp = w0 * xp[s4.x] + w1 * xp[s4.y] + w2 * xp[s4.z] + w3 * xp[s4.w];
                    a[reg] = mL[n * 128 + pxe] * (samp + t);
                    // bound gather clustering: <=16 loads in flight
                    if ((reg & 3) == 3) __builtin_amdgcn_sched_barrier(0);
                }
            } else {
                #pragma unroll
                for (int reg = 0; reg < 16; ++reg) a[reg] = 0.0f;
            }
        };
        epi(acc0, 0);
        epi(acc1, 1);

        __syncthreads();                    // prev out-GEMM Amod reads done
        // ---- scatter this pass's 128xN rows to Amod B-frag layout ----
        auto scat = [&](const f32x16& a, int j) {
            int nt = 2 * np + j;
            #pragma unroll
            for (int reg = 0; reg < 16; ++reg) {
                int rl = (reg & 3) + 8 * (reg >> 2) + 4 * (l >> 5);
                int k = g * 32 + rl;        // pass-local row
                *(unsigned short*)(Amod + ((k >> 4) * 4 + nt) * 1024
                                        + ((l & 31) + 32 * ((k >> 3) & 1)) * 16 + (k & 7) * 2)
                    = f2bf(a[reg]);
            }
        };
        scat(acc0, 0);
        scat(acc1, 1);
        __syncthreads();
        // ---- out-GEMM accumulate: oa += w_conv_chunk @ Amod ----
        #pragma unroll
        for (int ks8 = 0; ks8 < 8; ++ks8) {
            bf16x8 af = *(const bf16x8*)(wsbf + WS_ACONV
                            + (((ocT * 40 + p * 8 + ks8) * 64 + l) << 3));
            bf16x8 bf = *(bf16x8*)(Amod + (ks8 * 4 + nT2) * 1024 + l * 16);
            oa = MFMA32(af, bf, oa);
        }
    }

    // ---- final store: each out element written exactly once ----
    float* ob = out + (((size_t)b * 64) << 14) + (h << 7) + nT2 * 32 + (l & 31);
    #pragma unroll
    for (int reg = 0; reg < 16; ++reg) {
        int rl = (reg & 3) + 8 * (reg >> 2) + 4 * (l >> 5);
        int oc = ocT * 32 + rl;
        ob[(size_t)oc << 14] = oa[reg];
    }
}

extern "C" void kernel_launch(void* const* d_in, const int* in_sizes, int n_in,
                              void* d_out, int out_size, void* d_ws, size_t ws_size,
                              hipStream_t stream) {
    const float* x      = (const float*)d_in[0];
    const float* ref    = (const float*)d_in[1];
    const float* w_cd   = (const float*)d_in[2];
    const float* b_cd   = (const float*)d_in[3];
    const float* w_p    = (const float*)d_in[4];
    const float* b_p    = (const float*)d_in[5];
    const float* w_m    = (const float*)d_in[6];
    const float* b_m    = (const float*)d_in[7];
    const float* w_c    = (const float*)d_in[8];
    const float* b_c    = (const float*)d_in[9];
    const float* w_conv = (const float*)d_in[10];
    float* out = (float*)d_out;
    unsigned short* wsbf = (unsigned short*)d_ws;

    hipLaunchKernelGGL(prep_kernel, dim3(1704), dim3(256), 0, stream,
                       w_c, w_p, w_m, w_conv, w_cd, wsbf);
    hipLaunchKernelGGL(k2_fused, dim3(128, 4), dim3(256), 0, stream,
                       x, ref, b_cd, wsbf, wsbf);
    hipLaunchKernelGGL(k3_main, dim3(512), dim3(512), 0, stream,
                       x, b_c, b_p, b_m, wsbf, out);
}

// Round 4
// 371.331 us; speedup vs baseline: 2.6763x; 1.0585x over previous
//
#include <hip/hip_runtime.h>
#include <hip/hip_fp16.h>

// ColorDeformConv2d — round 8: kill the spill (256 regs/wave), 3 fat m-passes.
// vs r7: (1) __launch_bounds__(512,2): 256 unified regs/wave -> 80 acc + ~120
// arch fit with margin, no scratch (r6/r7's 490-550MB WRITE_SIZE was spill;
// occupancy 44% + first-dispatch 2.4% was scratch-capping). (2) 3 passes with
// acc[2][2] (2 m-tiles x 2 n-tiles) per wave: chunk-sweeps 108 -> 72, 8 MFMAs
// per staged chunk (was 4) to hide staging latency at the lower occupancy.
// (3) out-GEMM per pass runs as two 128-row sub-phases through the same 32K
// Amod buffer, identical k-accumulation order as r7 (bit-identical numerics).
//
// ws (u16 elems): A_c[20mt][36ks][64l][8] @0 (368640), A_pm @368640 (18432),
// A_conv[2][40][64][8] @387072 (40960), Wcd row-major @428032 (8192),
// fused2 @436224 (4*64*16384, cg-interleaved). Total 9.3 MB.
//
// k3 LDS (74496 B, 1 block/CU at 256 regs):
//   Bst0@0 8K | Bst1@8192 8K | Amod@16384 32K (uL f32 overlays first 16K,
//   dead after tables) | sidx@49152 9216 | w4h@58368 9216 | mL@67584 4608 |
//   bcL@72192 2304

typedef __attribute__((ext_vector_type(8))) __bf16 bf16x8;
typedef __attribute__((ext_vector_type(16))) float f32x16;
#define MFMA32(a, b, c) __builtin_amdgcn_mfma_f32_32x32x16_bf16((a), (b), (c), 0, 0, 0)

#define WS_AC    0
#define WS_APM   368640
#define WS_ACONV 387072
#define WS_WCD   428032
#define WS_F2    436224

__device__ __forceinline__ unsigned short f2bf(float f) {
    unsigned u = __float_as_uint(f);
    return (unsigned short)((u + 0x7FFFu + ((u >> 16) & 1u)) >> 16);   // RNE
}
__device__ __forceinline__ float fast_rcp(float x) {
#if __has_builtin(__builtin_amdgcn_rcpf)
    return __builtin_amdgcn_rcpf(x);
#else
    return 1.0f / x;
#endif
}
__device__ __forceinline__ float fast_tanh(float x) {
    float t = __expf(2.0f * x);
    return 1.0f - 2.0f * fast_rcp(t + 1.0f);
}
__device__ __forceinline__ float fast_sigmoid(float x) {
    return fast_rcp(1.0f + __expf(-x));
}

// ---------------- prep: weight repack to frag-order bf16 (unchanged) --------
__global__ void prep_kernel(const float* __restrict__ w_c, const float* __restrict__ w_p,
                            const float* __restrict__ w_m, const float* __restrict__ w_conv,
                            const float* __restrict__ w_cd, unsigned short* __restrict__ ws) {
    int i = blockIdx.x * 256 + threadIdx.x;
    if (i >= 436224) return;
    float val;
    if (i < WS_APM) {                       // A_c: row=gmt*32+(l&31), k'=ks*16+(l>>5)*8+j
        int t = i, j = t & 7, l = (t >> 3) & 63, r = t >> 9, ks = r % 36, gmt = r / 36;
        int row = gmt * 32 + (l & 31);
        int kp = ks * 16 + (l >> 5) * 8 + j, tap = kp >> 6, ci = kp & 63;
        val = (row < 576) ? w_c[row * 576 + ci * 9 + tap] : 0.0f;
    } else if (i < WS_ACONV) {              // A_pm: rows 0-17 w_p, 18-26 w_m
        int t = i - WS_APM, j = t & 7, l = (t >> 3) & 63, ks = t >> 9;
        int row = l & 31;
        int kp = ks * 16 + (l >> 5) * 8 + j, tap = kp >> 6, ci = kp & 63;
        val = (row < 18) ? w_p[row * 576 + ci * 9 + tap]
            : (row < 27) ? w_m[(row - 18) * 576 + ci * 9 + tap] : 0.0f;
    } else if (i < WS_WCD) {                // A_conv: k = U-row (natural order)
        int t = i - WS_ACONV, j = t & 7, l = (t >> 3) & 63, r = t >> 9;
        int gks = r % 40, ocT = r / 40;
        int oc = ocT * 32 + (l & 31);
        int krow = gks * 16 + (l >> 5) * 8 + j;
        val = (krow < 576) ? w_conv[oc * 576 + krow] : 0.0f;
    } else {                                // Wcd row-major [64][128]
        val = w_cd[i - WS_WCD];
    }
    ws[i] = f2bf(val);
}

// ------ im2col B-stage, split into load (global->reg) and write (reg->LDS) --
__device__ __forceinline__ uint4 stage_load(const unsigned short* f2b,
                                            int h, int chunk, int tid) {
    int tap = chunk >> 1;
    int dh = tap / 3 - 1, dw = tap % 3 - 1;
    int hs = h + dh;
    int kg = tid >> 7, px = tid & 127;      // 512 tasks: kg(4) x px(128)
    int cg = (chunk & 1) * 4 + kg;          // channels cg*8 .. cg*8+7
    int wsrc = px + dw;
    uint4 pk = {0u, 0u, 0u, 0u};
    if (((unsigned)hs < 128u) && ((unsigned)wsrc < 128u))
        pk = *(const uint4*)(f2b + (((size_t)cg << 14) + (hs << 7) + wsrc) * 8);
    return pk;
}
__device__ __forceinline__ void stage_write(char* Bst, uint4 pk, int tid) {
    int kg = tid >> 7, px = tid & 127;
    *(uint4*)(Bst + ((kg >> 1) * 4 + (px >> 5)) * 1024
                  + ((px & 31) + 32 * (kg & 1)) * 16) = pk;
}

// ---------------- k2: fused 1x1 conv -> fused2 cg-interleaved (unchanged) ----
__global__ __launch_bounds__(256, 4)
void k2_fused(const float* __restrict__ x, const float* __restrict__ ref,
              const float* __restrict__ b_cd, const unsigned short* __restrict__ wsbf,
              unsigned short* __restrict__ ws) {
    __shared__ __align__(16) char B0[32768];
    const int tid = threadIdx.x, l = tid & 63, w = tid >> 6;
    const int b = blockIdx.y, p0 = blockIdx.x * 128;
    const int rl31 = l & 31, kh8 = (l >> 5) * 8;

    #pragma unroll
    for (int it = 0; it < 8; ++it) {        // 2048 tasks: kg(16) x px(128)
        int task = it * 256 + tid;
        int kg = task >> 7, px = task & 127;
        const float* src = (kg < 8) ? x : ref;
        int kbase = (kg & 7) * 8;
        unsigned short v[8];
        #pragma unroll
        for (int j = 0; j < 8; ++j)
            v[j] = f2bf(src[(((size_t)b * 64 + kbase + j) << 14) + p0 + px]);
        uint4 pk;
        pk.x = (unsigned)v[0] | ((unsigned)v[1] << 16);
        pk.y = (unsigned)v[2] | ((unsigned)v[3] << 16);
        pk.z = (unsigned)v[4] | ((unsigned)v[5] << 16);
        pk.w = (unsigned)v[6] | ((unsigned)v[7] << 16);
        *(uint4*)(B0 + ((kg >> 1) * 4 + (px >> 5)) * 1024
                      + ((px & 31) + 32 * (kg & 1)) * 16) = pk;
    }
    __syncthreads();

    f32x16 a0, a1;
    #pragma unroll
    for (int r = 0; r < 16; ++r) { a0[r] = 0.0f; a1[r] = 0.0f; }
    const unsigned short* A0 = wsbf + WS_WCD + rl31 * 128 + kh8;
    #pragma unroll
    for (int s = 0; s < 8; ++s) {
        bf16x8 bf = *(bf16x8*)(B0 + ((s * 4 + w) * 64 + l) * 16);
        bf16x8 x0 = *(const bf16x8*)(A0 + s * 16);
        bf16x8 x1 = *(const bf16x8*)(A0 + 32 * 128 + s * 16);
        a0 = MFMA32(x0, bf, a0);
        a1 = MFMA32(x1, bf, a1);
    }
    unsigned short* f2 = ws + WS_F2 + ((size_t)b << 20);
    int px = p0 + w * 32 + rl31;
    int h4 = (l >> 5) * 4;
    #pragma unroll
    for (int t = 0; t < 2; ++t)
        #pragma unroll
        for (int q = 0; q < 4; ++q) {
            ushort4 st;
            float v0 = (t ? a1[q * 4 + 0] : a0[q * 4 + 0]) + b_cd[t * 32 + 8 * q + h4 + 0];
            float v1 = (t ? a1[q * 4 + 1] : a0[q * 4 + 1]) + b_cd[t * 32 + 8 * q + h4 + 1];
            float v2 = (t ? a1[q * 4 + 2] : a0[q * 4 + 2]) + b_cd[t * 32 + 8 * q + h4 + 2];
            float v3 = (t ? a1[q * 4 + 3] : a0[q * 4 + 3]) + b_cd[t * 32 + 8 * q + h4 + 3];
            st.x = f2bf(v0); st.y = f2bf(v1); st.z = f2bf(v2); st.w = f2bf(v3);
            *(ushort4*)(f2 + ((size_t)((t * 4 + q) << 14) + px) * 8 + h4) = st;
        }
}

// ---------------- k3: pm pre-phase + 3 fat m-passes, 256 regs/wave ----------
__global__ __launch_bounds__(512, 2)
void k3_main(const float* __restrict__ x, const float* __restrict__ b_c,
             const float* __restrict__ b_p, const float* __restrict__ b_m,
             const unsigned short* __restrict__ wsbf, float* __restrict__ out) {
    __shared__ __align__(16) char lds[74496];
    char* Bst0 = lds;
    char* Bst1 = lds + 8192;
    char* Amod = lds + 16384;
    float* uL = (float*)(lds + 16384);      // overlays Amod; dead after tables
    short* sidx = (short*)(lds + 49152);
    unsigned short* w4h = (unsigned short*)(lds + 58368);
    float* mL = (float*)(lds + 67584);
    float* bcL = (float*)(lds + 72192);

    const int tid = threadIdx.x, l = tid & 63, w = tid >> 6;
    const int g = w >> 1, np = w & 1;
    // XCD-banded decode: xcd = id&7 owns h band [xcd*16, xcd*16+16) x all b
    const int id = blockIdx.x;
    const int hbLin = (id & 7) * 64 + (id >> 3);
    const int b = hbLin & 3, h = hbLin >> 2;
    const unsigned short* f2b = wsbf + WS_F2 + ((size_t)b << 20);

    for (int i = tid; i < 576; i += 512) bcL[i] = b_c[i];

    // ================= pm pre-phase: U_pm[27][128] =================
    {
        f32x16 pm;
        #pragma unroll
        for (int r = 0; r < 16; ++r) pm[r] = 0.0f;
        uint4 pk = stage_load(f2b, h, 0, tid);
        stage_write(Bst0, pk, tid);
        __syncthreads();
        #pragma unroll 2
        for (int chunk = 0; chunk < 18; ++chunk) {
            char* cur = (chunk & 1) ? Bst1 : Bst0;
            char* nxt = (chunk & 1) ? Bst0 : Bst1;
            uint4 pknext;
            if (chunk < 17) pknext = stage_load(f2b, h, chunk + 1, tid);
            if (w < 4) {                    // wave w owns n-tile nt=w
                #pragma unroll
                for (int s = 0; s < 2; ++s) {
                    bf16x8 bf = *(bf16x8*)(cur + ((s * 4 + w) * 64 + l) * 16);
                    bf16x8 apm = *(const bf16x8*)(wsbf + WS_APM
                                    + (((chunk * 2 + s) * 64 + l) << 3));
                    pm = MFMA32(apm, bf, pm);
                }
            }
            if (chunk < 17) stage_write(nxt, pknext, tid);
            __syncthreads();
        }
        if (w < 4) {                        // pm -> uL (f32), nt = w
            int pxp = w * 32 + (l & 31);
            #pragma unroll
            for (int reg = 0; reg < 16; ++reg) {
                int rl = (reg & 3) + 8 * (reg >> 2) + 4 * (l >> 5);
                uL[rl * 128 + pxp] = pm[reg];
            }
        }
        __syncthreads();
    }

    // ================= tables from uL (built once per block) =================
    #pragma unroll 1
    for (int i = tid; i < 1152; i += 512) {
        int n = i >> 7, px = i & 127;
        float offr = uL[n * 128 + px] + b_p[n];
        float offc = uL[(9 + n) * 128 + px] + b_p[9 + n];
        float mraw = uL[(18 + n) * 128 + px] + b_m[n];
        int nr = n / 3, nc = n - nr * 3;
        float pr = (float)(h + nr) + offr;
        float pc = (float)(px + nc) + offc;
        float flr = floorf(pr), flc = floorf(pc);
        float qltr = fminf(fmaxf(flr, 0.0f), 129.0f);
        float qrbr = fminf(fmaxf(flr + 1.0f, 0.0f), 129.0f);
        float qltc = fminf(fmaxf(flc, 0.0f), 129.0f);
        float qrbc = fminf(fmaxf(flc + 1.0f, 0.0f), 129.0f);
        float prc = fminf(fmaxf(pr, 0.0f), 129.0f);
        float pcc = fminf(fmaxf(pc, 0.0f), 129.0f);
        float wltr = 1.0f + qltr - prc, wrbr = 1.0f - (qrbr - prc);
        float wltc = 1.0f + qltc - pcc, wrbc = 1.0f - (qrbc - pcc);
        int iltr = (int)qltr, irbr = (int)qrbr, iltc = (int)qltc, irbc = (int)qrbc;
        bool vlt_r = (iltr >= 1) && (iltr <= 128), vrb_r = (irbr >= 1) && (irbr <= 128);
        bool vlt_c = (iltc >= 1) && (iltc <= 128), vrb_c = (irbc >= 1) && (irbc <= 128);
        short4 s4; float4 f4;
        s4.x = (vlt_r && vlt_c) ? (short)(((iltr - 1) << 7) + (iltc - 1)) : (short)0;
        f4.x = (vlt_r && vlt_c) ? wltr * wltc : 0.0f;
        s4.y = (vrb_r && vrb_c) ? (short)(((irbr - 1) << 7) + (irbc - 1)) : (short)0;
        f4.y = (vrb_r && vrb_c) ? wrbr * wrbc : 0.0f;
        s4.z = (vlt_r && vrb_c) ? (short)(((iltr - 1) << 7) + (irbc - 1)) : (short)0;
        f4.z = (vlt_r && vrb_c) ? wltr * wrbc : 0.0f;
        s4.w = (vrb_r && vlt_c) ? (short)(((irbr - 1) << 7) + (iltc - 1)) : (short)0;
        f4.w = (vrb_r && vlt_c) ? wrbr * wltc : 0.0f;
        ((short4*)sidx)[px * 9 + n] = s4;
        int wb = (px * 9 + n) * 4;
        w4h[wb + 0] = __half_as_ushort(__float2half(f4.x));
        w4h[wb + 1] = __half_as_ushort(__float2half(f4.y));
        w4h[wb + 2] = __half_as_ushort(__float2half(f4.z));
        w4h[wb + 3] = __half_as_ushort(__float2half(f4.w));
        mL[n * 128 + px] = fast_sigmoid(mraw);
    }
    __syncthreads();

    // ================= 3 fat m-passes (8 m-tiles each; last is half) ========
    const int ocT = w >> 2, nT2 = w & 3;
    f32x16 oa;
    #pragma unroll
    for (int r = 0; r < 16; ++r) oa[r] = 0.0f;
    const float* xb = x + (((size_t)b * 64) << 14);

    #pragma unroll 1
    for (int p = 0; p < 3; ++p) {
        f32x16 acc[2][2];                   // [mi][j], all statically indexed
        #pragma unroll
        for (int mi = 0; mi < 2; ++mi)
            #pragma unroll
            for (int j = 0; j < 2; ++j)
                #pragma unroll
                for (int r = 0; r < 16; ++r) acc[mi][j][r] = 0.0f;

        // ---- U-GEMM k-loop, double-buffered, 1 barrier/chunk, 8 MFMA/chunk --
        {
            uint4 pk = stage_load(f2b, h, 0, tid);
            stage_write(Bst0, pk, tid);
            __syncthreads();
        }
        #pragma unroll 2
        for (int chunk = 0; chunk < 18; ++chunk) {
            char* cur = (chunk & 1) ? Bst1 : Bst0;
            char* nxt = (chunk & 1) ? Bst0 : Bst1;
            uint4 pknext;
            if (chunk < 17) pknext = stage_load(f2b, h, chunk + 1, tid);
            #pragma unroll
            for (int s = 0; s < 2; ++s) {
                const int ks = chunk * 2 + s;
                bf16x8 bf0 = *(bf16x8*)(cur + ((s * 4 + 2 * np) * 64 + l) * 16);
                bf16x8 bf1 = *(bf16x8*)(cur + ((s * 4 + 2 * np + 1) * 64 + l) * 16);
                #pragma unroll
                for (int mi = 0; mi < 2; ++mi) {
                    const int mt = p * 8 + mi * 4 + g;
                    if (mt < 20) {          // wave-uniform; only p=2,mi=1 skips
                        bf16x8 af = *(const bf16x8*)(wsbf + WS_AC
                                        + (((mt * 36 + ks) * 64 + l) << 3));
                        acc[mi][0] = MFMA32(af, bf0, acc[mi][0]);
                        acc[mi][1] = MFMA32(af, bf1, acc[mi][1]);
                    }
                }
            }
            if (chunk < 17) stage_write(nxt, pknext, tid);
            __syncthreads();
        }

        // ---- epilogue: tanh + bilinear sample + modulate (in regs) ----
        #pragma unroll
        for (int mi = 0; mi < 2; ++mi) {
            const int rowbase = (p * 8 + mi * 4 + g) * 32;
            #pragma unroll
            for (int j = 0; j < 2; ++j) {
                const int pxe = (2 * np + j) * 32 + (l & 31);
                if (rowbase < 576) {
                    #pragma unroll
                    for (int reg = 0; reg < 16; ++reg) {
                        int rl = (reg & 3) + 8 * (reg >> 2) + 4 * (l >> 5);
                        int row = rowbase + rl;
                        int c = row / 9, n = row - c * 9;
                        float uv = acc[mi][j][reg] + bcL[row];
                        float t = fast_tanh(uv);
                        short4 s4 = ((short4*)sidx)[pxe * 9 + n];
                        int wb = (pxe * 9 + n) * 4;
                        float w0 = __half2float(__ushort_as_half(w4h[wb + 0]));
                        float w1 = __half2float(__ushort_as_half(w4h[wb + 1]));
                        float w2 = __half2float(__ushort_as_half(w4h[wb + 2]));
                        float w3 = __half2float(__ushort_as_half(w4h[wb + 3]));
                        const float* xp = xb + ((size_t)c << 14);
                        float samp = w0 * xp[s4.x] + w1 * xp[s4.y]
                                   + w2 * xp[s4.z] + w3 * xp[s4.w];
                        acc[mi][j][reg] = mL[n * 128 + pxe] * (samp + t);
                        // bound gather clustering: <=16 loads in flight
                        if ((reg & 3) == 3) __builtin_amdgcn_sched_barrier(0);
                    }
                } else {
                    #pragma unroll
                    for (int reg = 0; reg < 16; ++reg) acc[mi][j][reg] = 0.0f;
                }
            }
        }

        // ---- two 128-row sub-phases: scatter -> out-GEMM accumulate ----
        #pragma unroll
        for (int mi = 0; mi < 2; ++mi) {
            const bool live = (p * 16 + mi * 8) < 40;   // block-uniform
            __syncthreads();                // prev Amod reads (or tables) done
            if (live) {
                #pragma unroll
                for (int j = 0; j < 2; ++j) {
                    int nt = 2 * np + j;
                    #pragma unroll
                    for (int reg = 0; reg < 16; ++reg) {
                        int rl = (reg & 3) + 8 * (reg >> 2) + 4 * (l >> 5);
                        int k = g * 32 + rl;            // sub-phase-local row
                        *(unsigned short*)(Amod + ((k >> 4) * 4 + nt) * 1024
                                + ((l & 31) + 32 * ((k >> 3) & 1)) * 16 + (k & 7) * 2)
                            = f2bf(acc[mi][j][reg]);
                    }
                }
            }
            __syncthreads();
            if (live) {
                #pragma unroll
                for (int ks8 = 0; ks8 < 8; ++ks8) {
                    bf16x8 af = *(const bf16x8*)(wsbf + WS_ACONV
                                    + (((ocT * 40 + p * 16 + mi * 8 + ks8) * 64 + l) << 3));
                    bf16x8 bf = *(bf16x8*)(Amod + (ks8 * 4 + nT2) * 1024 + l * 16);
                    oa = MFMA32(af, bf, oa);
                }
            }
        }
    }

    // ---- final store: each out element written exactly once ----
    float* ob = out + (((size_t)b * 64) << 14) + (h << 7) + nT2 * 32 + (l & 31);
    #pragma unroll
    for (int reg = 0; reg < 16; ++reg) {
        int rl = (reg & 3) + 8 * (reg >> 2) + 4 * (l >> 5);
        int oc = ocT * 32 + rl;
        ob[(size_t)oc << 14] = oa[reg];
    }
}

extern "C" void kernel_launch(void* const* d_in, const int* in_sizes, int n_in,
                              void* d_out, int out_size, void* d_ws, size_t ws_size,
                              hipStream_t stream) {
    const float* x      = (const float*)d_in[0];
    const float* ref    = (const float*)d_in[1];
    const float* w_cd   = (const float*)d_in[2];
    const float* b_cd   = (const float*)d_in[3];
    const float* w_p    = (const float*)d_in[4];
    const float* b_p    = (const float*)d_in[5];
    const float* w_m    = (const float*)d_in[6];
    const float* b_m    = (const float*)d_in[7];
    const float* w_c    = (const float*)d_in[8];
    const float* b_c    = (const float*)d_in[9];
    const float* w_conv = (const float*)d_in[10];
    float* out = (float*)d_out;
    unsigned short* wsbf = (unsigned short*)d_ws;

    hipLaunchKernelGGL(prep_kernel, dim3(1704), dim3(256), 0, stream,
                       w_c, w_p, w_m, w_conv, w_cd, wsbf);
    hipLaunchKernelGGL(k2_fused, dim3(128, 4), dim3(256), 0, stream,
                       x, ref, b_cd, wsbf, wsbf);
    hipLaunchKernelGGL(k3_main, dim3(512), dim3(512), 0, stream,
                       x, b_c, b_p, b_m, wsbf, out);
}

// Round 5
// 340.745 us; speedup vs baseline: 2.9165x; 1.0898x over previous
//
#include <hip/hip_runtime.h>
#include <hip/hip_fp16.h>

// ColorDeformConv2d — round 9: TLP for the latency-bound chunk loop.
// vs r8 (spill-free but 1 block/CU, barrier-serialized): (1) split each (h,b)
// row into two 64-px blocks of 256 threads -> 2 independent barrier domains
// co-resident per CU (8 waves total); per-wave regs unchanged (acc[2][2]+oa).
// (2) merge 2 chunks per staged iteration (8KB dbuf, 2 tasks/thread, 16
// MFMA/wave/iter) -> 9 barrier-iters per sweep (was 18). Same ks order ->
// bit-identical accumulation.
//
// ws (u16 elems): A_c[20mt][36ks][64l][8] @0 (368640), A_pm @368640 (18432),
// A_conv[2][40][64][8] @387072 (40960), Wcd row-major @428032 (8192),
// fused2 @436224 (4*64*16384, cg-interleaved). Total 9.3 MB.
//
// k3 LDS (46592 B): Bst0@0 8K | Bst1@8192 8K | Amod@16384 16K (uL 8K overlay,
// dead after tables) | sidx@32768 4608 | w4h@37376 4608 | mL@41984 2304 |
// bcL@44288 2304

typedef __attribute__((ext_vector_type(8))) __bf16 bf16x8;
typedef __attribute__((ext_vector_type(16))) float f32x16;
#define MFMA32(a, b, c) __builtin_amdgcn_mfma_f32_32x32x16_bf16((a), (b), (c), 0, 0, 0)

#define WS_AC    0
#define WS_APM   368640
#define WS_ACONV 387072
#define WS_WCD   428032
#define WS_F2    436224

__device__ __forceinline__ unsigned short f2bf(float f) {
    unsigned u = __float_as_uint(f);
    return (unsigned short)((u + 0x7FFFu + ((u >> 16) & 1u)) >> 16);   // RNE
}
__device__ __forceinline__ float fast_rcp(float x) {
#if __has_builtin(__builtin_amdgcn_rcpf)
    return __builtin_amdgcn_rcpf(x);
#else
    return 1.0f / x;
#endif
}
__device__ __forceinline__ float fast_tanh(float x) {
    float t = __expf(2.0f * x);
    return 1.0f - 2.0f * fast_rcp(t + 1.0f);
}
__device__ __forceinline__ float fast_sigmoid(float x) {
    return fast_rcp(1.0f + __expf(-x));
}

// ---------------- prep: weight repack to frag-order bf16 (unchanged) --------
__global__ void prep_kernel(const float* __restrict__ w_c, const float* __restrict__ w_p,
                            const float* __restrict__ w_m, const float* __restrict__ w_conv,
                            const float* __restrict__ w_cd, unsigned short* __restrict__ ws) {
    int i = blockIdx.x * 256 + threadIdx.x;
    if (i >= 436224) return;
    float val;
    if (i < WS_APM) {                       // A_c: row=gmt*32+(l&31), k'=ks*16+(l>>5)*8+j
        int t = i, j = t & 7, l = (t >> 3) & 63, r = t >> 9, ks = r % 36, gmt = r / 36;
        int row = gmt * 32 + (l & 31);
        int kp = ks * 16 + (l >> 5) * 8 + j, tap = kp >> 6, ci = kp & 63;
        val = (row < 576) ? w_c[row * 576 + ci * 9 + tap] : 0.0f;
    } else if (i < WS_ACONV) {              // A_pm: rows 0-17 w_p, 18-26 w_m
        int t = i - WS_APM, j = t & 7, l = (t >> 3) & 63, ks = t >> 9;
        int row = l & 31;
        int kp = ks * 16 + (l >> 5) * 8 + j, tap = kp >> 6, ci = kp & 63;
        val = (row < 18) ? w_p[row * 576 + ci * 9 + tap]
            : (row < 27) ? w_m[(row - 18) * 576 + ci * 9 + tap] : 0.0f;
    } else if (i < WS_WCD) {                // A_conv: k = U-row (natural order)
        int t = i - WS_ACONV, j = t & 7, l = (t >> 3) & 63, r = t >> 9;
        int gks = r % 40, ocT = r / 40;
        int oc = ocT * 32 + (l & 31);
        int krow = gks * 16 + (l >> 5) * 8 + j;
        val = (krow < 576) ? w_conv[oc * 576 + krow] : 0.0f;
    } else {                                // Wcd row-major [64][128]
        val = w_cd[i - WS_WCD];
    }
    ws[i] = f2bf(val);
}

// ------ im2col B-stage (64-px half): load global->reg, write reg->LDS -------
__device__ __forceinline__ uint4 stage_load64(const unsigned short* f2b, int h,
                                              int px0, int chunk, int tid) {
    int tap = chunk >> 1;
    int dh = tap / 3 - 1, dw = tap % 3 - 1;
    int hs = h + dh;
    int kg = tid >> 6, px = tid & 63;       // 256 tasks: kg(4) x px(64)
    int cg = (chunk & 1) * 4 + kg;          // channels cg*8 .. cg*8+7
    int wsrc = px0 + px + dw;
    uint4 pk = {0u, 0u, 0u, 0u};
    if (((unsigned)hs < 128u) && ((unsigned)wsrc < 128u))
        pk = *(const uint4*)(f2b + (((size_t)cg << 14) + (hs << 7) + wsrc) * 8);
    return pk;
}
__device__ __forceinline__ void stage_write64(char* Bst, uint4 pk, int c, int tid) {
    int kg = tid >> 6, px = tid & 63;
    *(uint4*)(Bst + c * 4096 + ((kg >> 1) * 2 + (px >> 5)) * 1024
                  + ((px & 31) + 32 * (kg & 1)) * 16) = pk;
}

// ---------------- k2: fused 1x1 conv -> fused2 cg-interleaved (unchanged) ----
__global__ __launch_bounds__(256, 4)
void k2_fused(const float* __restrict__ x, const float* __restrict__ ref,
              const float* __restrict__ b_cd, const unsigned short* __restrict__ wsbf,
              unsigned short* __restrict__ ws) {
    __shared__ __align__(16) char B0[32768];
    const int tid = threadIdx.x, l = tid & 63, w = tid >> 6;
    const int b = blockIdx.y, p0 = blockIdx.x * 128;
    const int rl31 = l & 31, kh8 = (l >> 5) * 8;

    #pragma unroll
    for (int it = 0; it < 8; ++it) {        // 2048 tasks: kg(16) x px(128)
        int task = it * 256 + tid;
        int kg = task >> 7, px = task & 127;
        const float* src = (kg < 8) ? x : ref;
        int kbase = (kg & 7) * 8;
        unsigned short v[8];
        #pragma unroll
        for (int j = 0; j < 8; ++j)
            v[j] = f2bf(src[(((size_t)b * 64 + kbase + j) << 14) + p0 + px]);
        uint4 pk;
        pk.x = (unsigned)v[0] | ((unsigned)v[1] << 16);
        pk.y = (unsigned)v[2] | ((unsigned)v[3] << 16);
        pk.z = (unsigned)v[4] | ((unsigned)v[5] << 16);
        pk.w = (unsigned)v[6] | ((unsigned)v[7] << 16);
        *(uint4*)(B0 + ((kg >> 1) * 4 + (px >> 5)) * 1024
                      + ((px & 31) + 32 * (kg & 1)) * 16) = pk;
    }
    __syncthreads();

    f32x16 a0, a1;
    #pragma unroll
    for (int r = 0; r < 16; ++r) { a0[r] = 0.0f; a1[r] = 0.0f; }
    const unsigned short* A0 = wsbf + WS_WCD + rl31 * 128 + kh8;
    #pragma unroll
    for (int s = 0; s < 8; ++s) {
        bf16x8 bf = *(bf16x8*)(B0 + ((s * 4 + w) * 64 + l) * 16);
        bf16x8 x0 = *(const bf16x8*)(A0 + s * 16);
        bf16x8 x1 = *(const bf16x8*)(A0 + 32 * 128 + s * 16);
        a0 = MFMA32(x0, bf, a0);
        a1 = MFMA32(x1, bf, a1);
    }
    unsigned short* f2 = ws + WS_F2 + ((size_t)b << 20);
    int px = p0 + w * 32 + rl31;
    int h4 = (l >> 5) * 4;
    #pragma unroll
    for (int t = 0; t < 2; ++t)
        #pragma unroll
        for (int q = 0; q < 4; ++q) {
            ushort4 st;
            float v0 = (t ? a1[q * 4 + 0] : a0[q * 4 + 0]) + b_cd[t * 32 + 8 * q + h4 + 0];
            float v1 = (t ? a1[q * 4 + 1] : a0[q * 4 + 1]) + b_cd[t * 32 + 8 * q + h4 + 1];
            float v2 = (t ? a1[q * 4 + 2] : a0[q * 4 + 2]) + b_cd[t * 32 + 8 * q + h4 + 2];
            float v3 = (t ? a1[q * 4 + 3] : a0[q * 4 + 3]) + b_cd[t * 32 + 8 * q + h4 + 3];
            st.x = f2bf(v0); st.y = f2bf(v1); st.z = f2bf(v2); st.w = f2bf(v3);
            *(ushort4*)(f2 + ((size_t)((t * 4 + q) << 14) + px) * 8 + h4) = st;
        }
}

// ---------------- k3: 64-px blocks (4 waves), 2-chunk iters, 3 m-passes -----
__global__ __launch_bounds__(256, 2)
void k3_main(const float* __restrict__ x, const float* __restrict__ b_c,
             const float* __restrict__ b_p, const float* __restrict__ b_m,
             const unsigned short* __restrict__ wsbf, float* __restrict__ out) {
    __shared__ __align__(16) char lds[46592];
    char* Bst0 = lds;
    char* Bst1 = lds + 8192;
    char* Amod = lds + 16384;
    float* uL = (float*)(lds + 16384);      // 8K overlay on Amod; dead after tables
    short* sidx = (short*)(lds + 32768);
    unsigned short* w4h = (unsigned short*)(lds + 37376);
    float* mL = (float*)(lds + 41984);
    float* bcL = (float*)(lds + 44288);

    const int tid = threadIdx.x, l = tid & 63, w = tid >> 6;   // 4 waves, g = w
    // XCD-banded decode: xcd = id&7 owns h band [xcd*16, xcd*16+16) x b x half
    const int id = blockIdx.x;
    const int hbLin = (id & 7) * 128 + (id >> 3);
    const int half = hbLin & 1, b = (hbLin >> 1) & 3, h = hbLin >> 3;
    const int px0 = half * 64;
    const unsigned short* f2b = wsbf + WS_F2 + ((size_t)b << 20);

    for (int i = tid; i < 576; i += 256) bcL[i] = b_c[i];

    // ================= pm pre-phase: U_pm[27][64] =================
    {
        f32x16 pm;
        #pragma unroll
        for (int r = 0; r < 16; ++r) pm[r] = 0.0f;
        stage_write64(Bst0, stage_load64(f2b, h, px0, 0, tid), 0, tid);
        stage_write64(Bst0, stage_load64(f2b, h, px0, 1, tid), 1, tid);
        __syncthreads();
        #pragma unroll 1
        for (int it = 0; it < 9; ++it) {
            char* cur = (it & 1) ? Bst1 : Bst0;
            char* nxt = (it & 1) ? Bst0 : Bst1;
            uint4 pkA, pkB;
            if (it < 8) {
                pkA = stage_load64(f2b, h, px0, 2 * it + 2, tid);
                pkB = stage_load64(f2b, h, px0, 2 * it + 3, tid);
            }
            if (w < 2) {                    // wave w owns n-tile nt=w
                #pragma unroll
                for (int c = 0; c < 2; ++c)
                    #pragma unroll
                    for (int s = 0; s < 2; ++s) {
                        int ks = 4 * it + 2 * c + s;
                        bf16x8 bf = *(bf16x8*)(cur + c * 4096 + ((s * 2 + w) * 64 + l) * 16);
                        bf16x8 apm = *(const bf16x8*)(wsbf + WS_APM + ((ks * 64 + l) << 3));
                        pm = MFMA32(apm, bf, pm);
                    }
            }
            if (it < 8) { stage_write64(nxt, pkA, 0, tid); stage_write64(nxt, pkB, 1, tid); }
            __syncthreads();
        }
        if (w < 2) {                        // pm -> uL (f32), nt = w
            int pxp = w * 32 + (l & 31);
            #pragma unroll
            for (int reg = 0; reg < 16; ++reg) {
                int rl = (reg & 3) + 8 * (reg >> 2) + 4 * (l >> 5);
                uL[rl * 64 + pxp] = pm[reg];
            }
        }
        __syncthreads();
    }

    // ================= tables from uL (once per block, 64 px) =================
    #pragma unroll 1
    for (int i = tid; i < 576; i += 256) {
        int n = i >> 6, px = i & 63;
        float offr = uL[n * 64 + px] + b_p[n];
        float offc = uL[(9 + n) * 64 + px] + b_p[9 + n];
        float mraw = uL[(18 + n) * 64 + px] + b_m[n];
        int nr = n / 3, nc = n - nr * 3;
        float pr = (float)(h + nr) + offr;
        float pc = (float)(px0 + px + nc) + offc;
        float flr = floorf(pr), flc = floorf(pc);
        float qltr = fminf(fmaxf(flr, 0.0f), 129.0f);
        float qrbr = fminf(fmaxf(flr + 1.0f, 0.0f), 129.0f);
        float qltc = fminf(fmaxf(flc, 0.0f), 129.0f);
        float qrbc = fminf(fmaxf(flc + 1.0f, 0.0f), 129.0f);
        float prc = fminf(fmaxf(pr, 0.0f), 129.0f);
        float pcc = fminf(fmaxf(pc, 0.0f), 129.0f);
        float wltr = 1.0f + qltr - prc, wrbr = 1.0f - (qrbr - prc);
        float wltc = 1.0f + qltc - pcc, wrbc = 1.0f - (qrbc - pcc);
        int iltr = (int)qltr, irbr = (int)qrbr, iltc = (int)qltc, irbc = (int)qrbc;
        bool vlt_r = (iltr >= 1) && (iltr <= 128), vrb_r = (irbr >= 1) && (irbr <= 128);
        bool vlt_c = (iltc >= 1) && (iltc <= 128), vrb_c = (irbc >= 1) && (irbc <= 128);
        short4 s4; float4 f4;
        s4.x = (vlt_r && vlt_c) ? (short)(((iltr - 1) << 7) + (iltc - 1)) : (short)0;
        f4.x = (vlt_r && vlt_c) ? wltr * wltc : 0.0f;
        s4.y = (vrb_r && vrb_c) ? (short)(((irbr - 1) << 7) + (irbc - 1)) : (short)0;
        f4.y = (vrb_r && vrb_c) ? wrbr * wrbc : 0.0f;
        s4.z = (vlt_r && vrb_c) ? (short)(((iltr - 1) << 7) + (irbc - 1)) : (short)0;
        f4.z = (vlt_r && vrb_c) ? wltr * wrbc : 0.0f;
        s4.w = (vrb_r && vlt_c) ? (short)(((irbr - 1) << 7) + (iltc - 1)) : (short)0;
        f4.w = (vrb_r && vlt_c) ? wrbr * wltc : 0.0f;
        ((short4*)sidx)[px * 9 + n] = s4;
        int wb = (px * 9 + n) * 4;
        w4h[wb + 0] = __half_as_ushort(__float2half(f4.x));
        w4h[wb + 1] = __half_as_ushort(__float2half(f4.y));
        w4h[wb + 2] = __half_as_ushort(__float2half(f4.z));
        w4h[wb + 3] = __half_as_ushort(__float2half(f4.w));
        mL[n * 64 + px] = fast_sigmoid(mraw);
    }
    __syncthreads();

    // ================= 3 fat m-passes =================
    f32x16 oa;
    #pragma unroll
    for (int r = 0; r < 16; ++r) oa[r] = 0.0f;
    const float* xb = x + (((size_t)b * 64) << 14);
    const int ocT = w >> 1, nT2 = w & 1;

    #pragma unroll 1
    for (int p = 0; p < 3; ++p) {
        f32x16 acc[2][2];                   // [mi][nt], statically indexed
        #pragma unroll
        for (int mi = 0; mi < 2; ++mi)
            #pragma unroll
            for (int j = 0; j < 2; ++j)
                #pragma unroll
                for (int r = 0; r < 16; ++r) acc[mi][j][r] = 0.0f;

        // ---- U-GEMM k-loop: 9 dbuf iters x 2 chunks, 1 barrier/iter ----
        stage_write64(Bst0, stage_load64(f2b, h, px0, 0, tid), 0, tid);
        stage_write64(Bst0, stage_load64(f2b, h, px0, 1, tid), 1, tid);
        __syncthreads();
        #pragma unroll 1
        for (int it = 0; it < 9; ++it) {
            char* cur = (it & 1) ? Bst1 : Bst0;
            char* nxt = (it & 1) ? Bst0 : Bst1;
            uint4 pkA, pkB;
            if (it < 8) {
                pkA = stage_load64(f2b, h, px0, 2 * it + 2, tid);
                pkB = stage_load64(f2b, h, px0, 2 * it + 3, tid);
            }
            #pragma unroll
            for (int c = 0; c < 2; ++c)
                #pragma unroll
                for (int s = 0; s < 2; ++s) {
                    const int ks = 4 * it + 2 * c + s;
                    bf16x8 bf0 = *(bf16x8*)(cur + c * 4096 + ((s * 2 + 0) * 64 + l) * 16);
                    bf16x8 bf1 = *(bf16x8*)(cur + c * 4096 + ((s * 2 + 1) * 64 + l) * 16);
                    #pragma unroll
                    for (int mi = 0; mi < 2; ++mi) {
                        const int mt = p * 8 + mi * 4 + w;
                        if (mt < 20) {      // wave-uniform; only p=2,mi=1 skips
                            bf16x8 af = *(const bf16x8*)(wsbf + WS_AC
                                            + (((mt * 36 + ks) * 64 + l) << 3));
                            acc[mi][0] = MFMA32(af, bf0, acc[mi][0]);
                            acc[mi][1] = MFMA32(af, bf1, acc[mi][1]);
                        }
                    }
                }
            if (it < 8) { stage_write64(nxt, pkA, 0, tid); stage_write64(nxt, pkB, 1, tid); }
            __syncthreads();
        }

        // ---- epilogue: tanh + bilinear sample + modulate (in regs) ----
        #pragma unroll
        for (int mi = 0; mi < 2; ++mi) {
            const int rowbase = (p * 8 + mi * 4 + w) * 32;
            #pragma unroll
            for (int j = 0; j < 2; ++j) {
                const int pxe = j * 32 + (l & 31);
                if (rowbase < 576) {
                    #pragma unroll
                    for (int reg = 0; reg < 16; ++reg) {
                        int rl = (reg & 3) + 8 * (reg >> 2) + 4 * (l >> 5);
                        int row = rowbase + rl;
                        int c = row / 9, n = row - c * 9;
                        float uv = acc[mi][j][reg] + bcL[row];
                        float t = fast_tanh(uv);
                        short4 s4 = ((short4*)sidx)[pxe * 9 + n];
                        int wb = (pxe * 9 + n) * 4;
                        float w0 = __half2float(__ushort_as_half(w4h[wb + 0]));
                        float w1 = __half2float(__ushort_as_half(w4h[wb + 1]));
                        float w2 = __half2float(__ushort_as_half(w4h[wb + 2]));
                        float w3 = __half2float(__ushort_as_half(w4h[wb + 3]));
                        const float* xp = xb + ((size_t)c << 14);
                        float samp = w0 * xp[s4.x] + w1 * xp[s4.y]
                                   + w2 * xp[s4.z] + w3 * xp[s4.w];
                        acc[mi][j][reg] = mL[n * 64 + pxe] * (samp + t);
                        // bound gather clustering: <=16 loads in flight
                        if ((reg & 3) == 3) __builtin_amdgcn_sched_barrier(0);
                    }
                } else {
                    #pragma unroll
                    for (int reg = 0; reg < 16; ++reg) acc[mi][j][reg] = 0.0f;
                }
            }
        }

        // ---- two 128-row sub-phases: scatter -> out-GEMM accumulate ----
        #pragma unroll
        for (int mi = 0; mi < 2; ++mi) {
            const bool live = (p * 16 + mi * 8) < 40;   // block-uniform
            __syncthreads();                // prev Amod reads (or tables) done
            if (live) {
                #pragma unroll
                for (int j = 0; j < 2; ++j) {
                    #pragma unroll
                    for (int reg = 0; reg < 16; ++reg) {
                        int rl = (reg & 3) + 8 * (reg >> 2) + 4 * (l >> 5);
                        int k = w * 32 + rl;            // sub-phase-local row
                        *(unsigned short*)(Amod + ((k >> 4) * 2 + j) * 1024
                                + ((l & 31) + 32 * ((k >> 3) & 1)) * 16 + (k & 7) * 2)
                            = f2bf(acc[mi][j][reg]);
                    }
                }
            }
            __syncthreads();
            if (live) {
                #pragma unroll
                for (int ks8 = 0; ks8 < 8; ++ks8) {
                    bf16x8 af = *(const bf16x8*)(wsbf + WS_ACONV
                                    + (((ocT * 40 + p * 16 + mi * 8 + ks8) * 64 + l) << 3));
                    bf16x8 bf = *(bf16x8*)(Amod + (ks8 * 2 + nT2) * 1024 + l * 16);
                    oa = MFMA32(af, bf, oa);
                }
            }
        }
    }

    // ---- final store: each out element written exactly once ----
    float* ob = out + (((size_t)b * 64) << 14) + (h << 7) + px0 + nT2 * 32 + (l & 31);
    #pragma unroll
    for (int reg = 0; reg < 16; ++reg) {
        int rl = (reg & 3) + 8 * (reg >> 2) + 4 * (l >> 5);
        int oc = ocT * 32 + rl;
        ob[(size_t)oc << 14] = oa[reg];
    }
}

extern "C" void kernel_launch(void* const* d_in, const int* in_sizes, int n_in,
                              void* d_out, int out_size, void* d_ws, size_t ws_size,
                              hipStream_t stream) {
    const float* x      = (const float*)d_in[0];
    const float* ref    = (const float*)d_in[1];
    const float* w_cd   = (const float*)d_in[2];
    const float* b_cd   = (const float*)d_in[3];
    const float* w_p    = (const float*)d_in[4];
    const float* b_p    = (const float*)d_in[5];
    const float* w_m    = (const float*)d_in[6];
    const float* b_m    = (const float*)d_in[7];
    const float* w_c    = (const float*)d_in[8];
    const float* b_c    = (const float*)d_in[9];
    const float* w_conv = (const float*)d_in[10];
    float* out = (float*)d_out;
    unsigned short* wsbf = (unsigned short*)d_ws;

    hipLaunchKernelGGL(prep_kernel, dim3(1704), dim3(256), 0, stream,
                       w_c, w_p, w_m, w_conv, w_cd, wsbf);
    hipLaunchKernelGGL(k2_fused, dim3(128, 4), dim3(256), 0, stream,
                       x, ref, b_cd, wsbf, wsbf);
    hipLaunchKernelGGL(k3_main, dim3(1024), dim3(256), 0, stream,
                       x, b_c, b_p, b_m, wsbf, out);
}

// Round 6
// 310.316 us; speedup vs baseline: 3.2025x; 1.0981x over previous
//
#include <hip/hip_runtime.h>
#include <hip/hip_fp16.h>

// ColorDeformConv2d — round 10: halve the gather + 4 blocks/CU zero-tail.
// vs r9: (1) bilinear via 2x float2 pair-loads (adjacent col corners share a
// load); col validity/clamp folded into precomputed weights. Gather wave-inst
// count halves. (2) single-chunk staged iters (Bst 2x4K) + short2 sidx ->
// LDS 36.1KB -> 4 blocks/CU resident = grid's exact 4/CU, no tail round;
// gather phase of one block overlaps MFMA phase of another.
//
// ws (u16 elems): A_c[20mt][36ks][64l][8] @0 (368640), A_pm @368640 (18432),
// A_conv[2][40][64][8] @387072 (40960), Wcd row-major @428032 (8192),
// fused2 @436224 (4*64*16384, cg-interleaved). Total 9.3 MB.
//
// k3 LDS (36096 B, 4 blocks/CU): Bst0@0 4K | Bst1@4096 4K | Amod@8192 16K
// (uL 6.9K overlay, dead after tables) | sidx@24576 2304 | w4h@26880 4608 |
// mL@31488 2304 | bcL@33792 2304

typedef __attribute__((ext_vector_type(8))) __bf16 bf16x8;
typedef __attribute__((ext_vector_type(16))) float f32x16;
#define MFMA32(a, b, c) __builtin_amdgcn_mfma_f32_32x32x16_bf16((a), (b), (c), 0, 0, 0)

#define WS_AC    0
#define WS_APM   368640
#define WS_ACONV 387072
#define WS_WCD   428032
#define WS_F2    436224

struct f2pair { float x, y; };              // align 4: legal unaligned-8 load

__device__ __forceinline__ unsigned short f2bf(float f) {
    unsigned u = __float_as_uint(f);
    return (unsigned short)((u + 0x7FFFu + ((u >> 16) & 1u)) >> 16);   // RNE
}
__device__ __forceinline__ float fast_rcp(float x) {
#if __has_builtin(__builtin_amdgcn_rcpf)
    return __builtin_amdgcn_rcpf(x);
#else
    return 1.0f / x;
#endif
}
__device__ __forceinline__ float fast_tanh(float x) {
    float t = __expf(2.0f * x);
    return 1.0f - 2.0f * fast_rcp(t + 1.0f);
}
__device__ __forceinline__ float fast_sigmoid(float x) {
    return fast_rcp(1.0f + __expf(-x));
}

// ---------------- prep: weight repack to frag-order bf16 (unchanged) --------
__global__ void prep_kernel(const float* __restrict__ w_c, const float* __restrict__ w_p,
                            const float* __restrict__ w_m, const float* __restrict__ w_conv,
                            const float* __restrict__ w_cd, unsigned short* __restrict__ ws) {
    int i = blockIdx.x * 256 + threadIdx.x;
    if (i >= 436224) return;
    float val;
    if (i < WS_APM) {                       // A_c: row=gmt*32+(l&31), k'=ks*16+(l>>5)*8+j
        int t = i, j = t & 7, l = (t >> 3) & 63, r = t >> 9, ks = r % 36, gmt = r / 36;
        int row = gmt * 32 + (l & 31);
        int kp = ks * 16 + (l >> 5) * 8 + j, tap = kp >> 6, ci = kp & 63;
        val = (row < 576) ? w_c[row * 576 + ci * 9 + tap] : 0.0f;
    } else if (i < WS_ACONV) {              // A_pm: rows 0-17 w_p, 18-26 w_m
        int t = i - WS_APM, j = t & 7, l = (t >> 3) & 63, ks = t >> 9;
        int row = l & 31;
        int kp = ks * 16 + (l >> 5) * 8 + j, tap = kp >> 6, ci = kp & 63;
        val = (row < 18) ? w_p[row * 576 + ci * 9 + tap]
            : (row < 27) ? w_m[(row - 18) * 576 + ci * 9 + tap] : 0.0f;
    } else if (i < WS_WCD) {                // A_conv: k = U-row (natural order)
        int t = i - WS_ACONV, j = t & 7, l = (t >> 3) & 63, r = t >> 9;
        int gks = r % 40, ocT = r / 40;
        int oc = ocT * 32 + (l & 31);
        int krow = gks * 16 + (l >> 5) * 8 + j;
        val = (krow < 576) ? w_conv[oc * 576 + krow] : 0.0f;
    } else {                                // Wcd row-major [64][128]
        val = w_cd[i - WS_WCD];
    }
    ws[i] = f2bf(val);
}

// ------ im2col B-stage (64-px, single 32-k' chunk): global->reg, reg->LDS ----
__device__ __forceinline__ uint4 stage_load64(const unsigned short* f2b, int h,
                                              int px0, int chunk, int tid) {
    int tap = chunk >> 1;
    int dh = tap / 3 - 1, dw = tap % 3 - 1;
    int hs = h + dh;
    int kg = tid >> 6, px = tid & 63;       // 256 tasks: kg(4) x px(64)
    int cg = (chunk & 1) * 4 + kg;          // channels cg*8 .. cg*8+7
    int wsrc = px0 + px + dw;
    uint4 pk = {0u, 0u, 0u, 0u};
    if (((unsigned)hs < 128u) && ((unsigned)wsrc < 128u))
        pk = *(const uint4*)(f2b + (((size_t)cg << 14) + (hs << 7) + wsrc) * 8);
    return pk;
}
__device__ __forceinline__ void stage_write64(char* Bst, uint4 pk, int tid) {
    int kg = tid >> 6, px = tid & 63;
    *(uint4*)(Bst + ((kg >> 1) * 2 + (px >> 5)) * 1024
                  + ((px & 31) + 32 * (kg & 1)) * 16) = pk;
}

// ---------------- k2: fused 1x1 conv -> fused2 cg-interleaved (unchanged) ----
__global__ __launch_bounds__(256, 4)
void k2_fused(const float* __restrict__ x, const float* __restrict__ ref,
              const float* __restrict__ b_cd, const unsigned short* __restrict__ wsbf,
              unsigned short* __restrict__ ws) {
    __shared__ __align__(16) char B0[32768];
    const int tid = threadIdx.x, l = tid & 63, w = tid >> 6;
    const int b = blockIdx.y, p0 = blockIdx.x * 128;
    const int rl31 = l & 31, kh8 = (l >> 5) * 8;

    #pragma unroll
    for (int it = 0; it < 8; ++it) {        // 2048 tasks: kg(16) x px(128)
        int task = it * 256 + tid;
        int kg = task >> 7, px = task & 127;
        const float* src = (kg < 8) ? x : ref;
        int kbase = (kg & 7) * 8;
        unsigned short v[8];
        #pragma unroll
        for (int j = 0; j < 8; ++j)
            v[j] = f2bf(src[(((size_t)b * 64 + kbase + j) << 14) + p0 + px]);
        uint4 pk;
        pk.x = (unsigned)v[0] | ((unsigned)v[1] << 16);
        pk.y = (unsigned)v[2] | ((unsigned)v[3] << 16);
        pk.z = (unsigned)v[4] | ((unsigned)v[5] << 16);
        pk.w = (unsigned)v[6] | ((unsigned)v[7] << 16);
        *(uint4*)(B0 + ((kg >> 1) * 4 + (px >> 5)) * 1024
                      + ((px & 31) + 32 * (kg & 1)) * 16) = pk;
    }
    __syncthreads();

    f32x16 a0, a1;
    #pragma unroll
    for (int r = 0; r < 16; ++r) { a0[r] = 0.0f; a1[r] = 0.0f; }
    const unsigned short* A0 = wsbf + WS_WCD + rl31 * 128 + kh8;
    #pragma unroll
    for (int s = 0; s < 8; ++s) {
        bf16x8 bf = *(bf16x8*)(B0 + ((s * 4 + w) * 64 + l) * 16);
        bf16x8 x0 = *(const bf16x8*)(A0 + s * 16);
        bf16x8 x1 = *(const bf16x8*)(A0 + 32 * 128 + s * 16);
        a0 = MFMA32(x0, bf, a0);
        a1 = MFMA32(x1, bf, a1);
    }
    unsigned short* f2 = ws + WS_F2 + ((size_t)b << 20);
    int px = p0 + w * 32 + rl31;
    int h4 = (l >> 5) * 4;
    #pragma unroll
    for (int t = 0; t < 2; ++t)
        #pragma unroll
        for (int q = 0; q < 4; ++q) {
            ushort4 st;
            float v0 = (t ? a1[q * 4 + 0] : a0[q * 4 + 0]) + b_cd[t * 32 + 8 * q + h4 + 0];
            float v1 = (t ? a1[q * 4 + 1] : a0[q * 4 + 1]) + b_cd[t * 32 + 8 * q + h4 + 1];
            float v2 = (t ? a1[q * 4 + 2] : a0[q * 4 + 2]) + b_cd[t * 32 + 8 * q + h4 + 2];
            float v3 = (t ? a1[q * 4 + 3] : a0[q * 4 + 3]) + b_cd[t * 32 + 8 * q + h4 + 3];
            st.x = f2bf(v0); st.y = f2bf(v1); st.z = f2bf(v2); st.w = f2bf(v3);
            *(ushort4*)(f2 + ((size_t)((t * 4 + q) << 14) + px) * 8 + h4) = st;
        }
}

// ---------------- k3: 64-px blocks, pair-load gathers, 4 blocks/CU ----------
__global__ __launch_bounds__(256, 4)
void k3_main(const float* __restrict__ x, const float* __restrict__ b_c,
             const float* __restrict__ b_p, const float* __restrict__ b_m,
             const unsigned short* __restrict__ wsbf, float* __restrict__ out) {
    __shared__ __align__(16) char lds[36096];
    char* Bst0 = lds;
    char* Bst1 = lds + 4096;
    char* Amod = lds + 8192;
    float* uL = (float*)(lds + 8192);       // 6.9K overlay; dead after tables
    short* sidx = (short*)(lds + 24576);
    unsigned short* w4h = (unsigned short*)(lds + 26880);
    float* mL = (float*)(lds + 31488);
    float* bcL = (float*)(lds + 33792);

    const int tid = threadIdx.x, l = tid & 63, w = tid >> 6;   // 4 waves
    // XCD-banded decode: xcd = id&7 owns h band [xcd*16, xcd*16+16) x b x half
    const int id = blockIdx.x;
    const int hbLin = (id & 7) * 128 + (id >> 3);
    const int half = hbLin & 1, b = (hbLin >> 1) & 3, h = hbLin >> 3;
    const int px0 = half * 64;
    const unsigned short* f2b = wsbf + WS_F2 + ((size_t)b << 20);

    for (int i = tid; i < 576; i += 256) bcL[i] = b_c[i];

    // ================= pm pre-phase: U_pm[27][64] =================
    {
        f32x16 pm;
        #pragma unroll
        for (int r = 0; r < 16; ++r) pm[r] = 0.0f;
        stage_write64(Bst0, stage_load64(f2b, h, px0, 0, tid), tid);
        __syncthreads();
        #pragma unroll 1
        for (int it = 0; it < 18; ++it) {
            char* cur = (it & 1) ? Bst1 : Bst0;
            char* nxt = (it & 1) ? Bst0 : Bst1;
            uint4 pk;
            if (it < 17) pk = stage_load64(f2b, h, px0, it + 1, tid);
            if (w < 2) {                    // wave w owns n-tile nt=w
                #pragma unroll
                for (int s = 0; s < 2; ++s) {
                    int ks = it * 2 + s;
                    bf16x8 bf = *(bf16x8*)(cur + ((s * 2 + w) * 64 + l) * 16);
                    bf16x8 apm = *(const bf16x8*)(wsbf + WS_APM + ((ks * 64 + l) << 3));
                    pm = MFMA32(apm, bf, pm);
                }
            }
            if (it < 17) stage_write64(nxt, pk, tid);
            __syncthreads();
        }
        if (w < 2) {                        // pm -> uL (f32), nt = w
            int pxp = w * 32 + (l & 31);
            #pragma unroll
            for (int reg = 0; reg < 16; ++reg) {
                int rl = (reg & 3) + 8 * (reg >> 2) + 4 * (l >> 5);
                uL[rl * 64 + pxp] = pm[reg];
            }
        }
        __syncthreads();
    }

    // ============ tables from uL: pair-based bilinear (once per block) =======
    #pragma unroll 1
    for (int i = tid; i < 576; i += 256) {
        int n = i >> 6, px = i & 63;
        float offr = uL[n * 64 + px] + b_p[n];
        float offc = uL[(9 + n) * 64 + px] + b_p[9 + n];
        float mraw = uL[(18 + n) * 64 + px] + b_m[n];
        int nr = n / 3, nc = n - nr * 3;
        float pr = (float)(h + nr) + offr;
        float pc = (float)(px0 + px + nc) + offc;
        float flr = floorf(pr), flc = floorf(pc);
        float prc = fminf(fmaxf(pr, 0.0f), 129.0f);
        float pcc = fminf(fmaxf(pc, 0.0f), 129.0f);
        // rows
        float q0r = fminf(fmaxf(flr, 0.0f), 129.0f);
        float q1r = fminf(fmaxf(flr + 1.0f, 0.0f), 129.0f);
        int ir0 = (int)q0r, ir1 = (int)q1r;
        bool vr0 = (ir0 >= 1) && (ir0 <= 128), vr1 = (ir1 >= 1) && (ir1 <= 128);
        float wr0 = vr0 ? (1.0f + q0r - prc) : 0.0f;
        float wr1 = vr1 ? (1.0f - (q1r - prc)) : 0.0f;
        // cols
        float q0c = fminf(fmaxf(flc, 0.0f), 129.0f);
        float q1c = fminf(fmaxf(flc + 1.0f, 0.0f), 129.0f);
        int ic0 = (int)q0c, ic1 = (int)q1c;
        bool vc0 = (ic0 >= 1) && (ic0 <= 128), vc1 = (ic1 >= 1) && (ic1 <= 128);
        float wc0 = vc0 ? (1.0f + q0c - pcc) : 0.0f;
        float wc1 = vc1 ? (1.0f - (q1c - pcc)) : 0.0f;
        // pair base in x-coords; fold clamp-remap + validity into slot weights
        int cx0 = ic0 - 1, cx1 = ic1 - 1;
        int base = min(max(cx0, 0), 126);
        float ws0 = ((base == cx0) && vc0 ? wc0 : 0.0f)
                  + ((base == cx1) && vc1 ? wc1 : 0.0f);
        float ws1 = ((base + 1 == cx0) && vc0 ? wc0 : 0.0f)
                  + ((base + 1 == cx1) && vc1 ? wc1 : 0.0f);
        int rx0 = min(max(ir0 - 1, 0), 127), rx1 = min(max(ir1 - 1, 0), 127);
        short2 s2;
        s2.x = (short)(rx0 * 128 + base);
        s2.y = (short)(rx1 * 128 + base);
        ((short2*)sidx)[px * 9 + n] = s2;
        int wb = (px * 9 + n) * 4;
        w4h[wb + 0] = __half_as_ushort(__float2half(wr0 * ws0));
        w4h[wb + 1] = __half_as_ushort(__float2half(wr0 * ws1));
        w4h[wb + 2] = __half_as_ushort(__float2half(wr1 * ws0));
        w4h[wb + 3] = __half_as_ushort(__float2half(wr1 * ws1));
        mL[n * 64 + px] = fast_sigmoid(mraw);
    }
    __syncthreads();

    // ================= 3 fat m-passes =================
    f32x16 oa;
    #pragma unroll
    for (int r = 0; r < 16; ++r) oa[r] = 0.0f;
    const float* xb = x + (((size_t)b * 64) << 14);
    const int ocT = w >> 1, nT2 = w & 1;

    #pragma unroll 1
    for (int p = 0; p < 3; ++p) {
        f32x16 acc[2][2];                   // [mi][nt], statically indexed
        #pragma unroll
        for (int mi = 0; mi < 2; ++mi)
            #pragma unroll
            for (int j = 0; j < 2; ++j)
                #pragma unroll
                for (int r = 0; r < 16; ++r) acc[mi][j][r] = 0.0f;

        // ---- U-GEMM k-loop: 18 dbuf iters, 8 MFMA/wave/iter ----
        stage_write64(Bst0, stage_load64(f2b, h, px0, 0, tid), tid);
        __syncthreads();
        #pragma unroll 1
        for (int it = 0; it < 18; ++it) {
            char* cur = (it & 1) ? Bst1 : Bst0;
            char* nxt = (it & 1) ? Bst0 : Bst1;
            uint4 pk;
            if (it < 17) pk = stage_load64(f2b, h, px0, it + 1, tid);
            #pragma unroll
            for (int s = 0; s < 2; ++s) {
                const int ks = it * 2 + s;
                bf16x8 bf0 = *(bf16x8*)(cur + ((s * 2 + 0) * 64 + l) * 16);
                bf16x8 bf1 = *(bf16x8*)(cur + ((s * 2 + 1) * 64 + l) * 16);
                #pragma unroll
                for (int mi = 0; mi < 2; ++mi) {
                    const int mt = p * 8 + mi * 4 + w;
                    if (mt < 20) {          // wave-uniform; only p=2,mi=1 skips
                        bf16x8 af = *(const bf16x8*)(wsbf + WS_AC
                                        + (((mt * 36 + ks) * 64 + l) << 3));
                        acc[mi][0] = MFMA32(af, bf0, acc[mi][0]);
                        acc[mi][1] = MFMA32(af, bf1, acc[mi][1]);
                    }
                }
            }
            if (it < 17) stage_write64(nxt, pk, tid);
            __syncthreads();
        }

        // ---- epilogue: tanh + pair-load bilinear + modulate (in regs) ----
        #pragma unroll
        for (int mi = 0; mi < 2; ++mi) {
            const int rowbase = (p * 8 + mi * 4 + w) * 32;
            #pragma unroll
            for (int j = 0; j < 2; ++j) {
                const int pxe = j * 32 + (l & 31);
                if (rowbase < 576) {
                    #pragma unroll
                    for (int reg = 0; reg < 16; ++reg) {
                        int rl = (reg & 3) + 8 * (reg >> 2) + 4 * (l >> 5);
                        int row = rowbase + rl;
                        int c = row / 9, n = row - c * 9;
                        float uv = acc[mi][j][reg] + bcL[row];
                        float t = fast_tanh(uv);
                        short2 s2 = ((short2*)sidx)[pxe * 9 + n];
                        int wb = (pxe * 9 + n) * 4;
                        float w0 = __half2float(__ushort_as_half(w4h[wb + 0]));
                        float w1 = __half2float(__ushort_as_half(w4h[wb + 1]));
                        float w2 = __half2float(__ushort_as_half(w4h[wb + 2]));
                        float w3 = __half2float(__ushort_as_half(w4h[wb + 3]));
                        const float* xp = xb + ((size_t)c << 14);
                        f2pair v0 = *(const f2pair*)(xp + s2.x);
                        f2pair v1 = *(const f2pair*)(xp + s2.y);
                        float samp = w0 * v0.x + w1 * v0.y + w2 * v1.x + w3 * v1.y;
                        acc[mi][j][reg] = mL[n * 64 + pxe] * (samp + t);
                        // bound gather clustering: <=16 loads in flight
                        if ((reg & 7) == 7) __builtin_amdgcn_sched_barrier(0);
                    }
                } else {
                    #pragma unroll
                    for (int reg = 0; reg < 16; ++reg) acc[mi][j][reg] = 0.0f;
                }
            }
        }

        // ---- two 128-row sub-phases: scatter -> out-GEMM accumulate ----
        #pragma unroll
        for (int mi = 0; mi < 2; ++mi) {
            const bool live = (p * 16 + mi * 8) < 40;   // block-uniform
            __syncthreads();                // prev Amod reads (or tables) done
            if (live) {
                #pragma unroll
                for (int j = 0; j < 2; ++j) {
                    #pragma unroll
                    for (int reg = 0; reg < 16; ++reg) {
                        int rl = (reg & 3) + 8 * (reg >> 2) + 4 * (l >> 5);
                        int k = w * 32 + rl;            // sub-phase-local row
                        *(unsigned short*)(Amod + ((k >> 4) * 2 + j) * 1024
                                + ((l & 31) + 32 * ((k >> 3) & 1)) * 16 + (k & 7) * 2)
                            = f2bf(acc[mi][j][reg]);
                    }
                }
            }
            __syncthreads();
            if (live) {
                #pragma unroll
                for (int ks8 = 0; ks8 < 8; ++ks8) {
                    bf16x8 af = *(const bf16x8*)(wsbf + WS_ACONV
                                    + (((ocT * 40 + p * 16 + mi * 8 + ks8) * 64 + l) << 3));
                    bf16x8 bf = *(bf16x8*)(Amod + (ks8 * 2 + nT2) * 1024 + l * 16);
                    oa = MFMA32(af, bf, oa);
                }
            }
        }
    }

    // ---- final store: each out element written exactly once ----
    float* ob = out + (((size_t)b * 64) << 14) + (h << 7) + px0 + nT2 * 32 + (l & 31);
    #pragma unroll
    for (int reg = 0; reg < 16; ++reg) {
        int rl = (reg & 3) + 8 * (reg >> 2) + 4 * (l >> 5);
        int oc = ocT * 32 + rl;
        ob[(size_t)oc << 14] = oa[reg];
    }
}

extern "C" void kernel_launch(void* const* d_in, const int* in_sizes, int n_in,
                              void* d_out, int out_size, void* d_ws, size_t ws_size,
                              hipStream_t stream) {
    const float* x      = (const float*)d_in[0];
    const float* ref    = (const float*)d_in[1];
    const float* w_cd   = (const float*)d_in[2];
    const float* b_cd   = (const float*)d_in[3];
    const float* w_p    = (const float*)d_in[4];
    const float* b_p    = (const float*)d_in[5];
    const float* w_m    = (const float*)d_in[6];
    const float* b_m    = (const float*)d_in[7];
    const float* w_c    = (const float*)d_in[8];
    const float* b_c    = (const float*)d_in[9];
    const float* w_conv = (const float*)d_in[10];
    float* out = (float*)d_out;
    unsigned short* wsbf = (unsigned short*)d_ws;

    hipLaunchKernelGGL(prep_kernel, dim3(1704), dim3(256), 0, stream,
                       w_c, w_p, w_m, w_conv, w_cd, wsbf);
    hipLaunchKernelGGL(k2_fused, dim3(128, 4), dim3(256), 0, stream,
                       x, ref, b_cd, wsbf, wsbf);
    hipLaunchKernelGGL(k3_main, dim3(1024), dim3(256), 0, stream,
                       x, b_c, b_p, b_m, wsbf, out);
}

// Round 7
// 223.878 us; speedup vs baseline: 4.4390x; 1.3861x over previous
//
#include <hip/hip_runtime.h>
#include <hip/hip_fp16.h>

// ColorDeformConv2d — round 11: 4 blocks/CU *without* spill.
// vs r10 (pair-load gather + 4 domains, but 80 acc regs under a 128 cap ->
// spill): 5 thin m-passes, acc[2]+oa = 48 acc regs -> 80 arch free at
// __launch_bounds__(256,4). Gathers bounded to <=8 in flight. 20 m-tiles map
// exactly to 5 passes x 4 waves (no dead slots); out-GEMM 1 sub-phase/pass,
// same gks ascending order -> bit-identical accumulation.
//
// Reg-pool model (measured r8/r9/r10): 512 regs/SIMD effective;
// 128/wave -> 4 waves/SIMD -> 4 blocks/CU (grid is exactly 4/CU, no tail).
//
// ws (u16 elems): A_c[20mt][36ks][64l][8] @0 (368640), A_pm @368640 (18432),
// A_conv[2][40][64][8] @387072 (40960), Wcd row-major @428032 (8192),
// fused2 @436224 (4*64*16384, cg-interleaved). Total 9.3 MB.
//
// k3 LDS (36096 B, 4 blocks/CU): Bst0@0 4K | Bst1@4096 4K | Amod@8192 16K
// (uL 6.9K overlay, dead after tables) | sidx@24576 2304 | w4h@26880 4608 |
// mL@31488 2304 | bcL@33792 2304

typedef __attribute__((ext_vector_type(8))) __bf16 bf16x8;
typedef __attribute__((ext_vector_type(16))) float f32x16;
#define MFMA32(a, b, c) __builtin_amdgcn_mfma_f32_32x32x16_bf16((a), (b), (c), 0, 0, 0)

#define WS_AC    0
#define WS_APM   368640
#define WS_ACONV 387072
#define WS_WCD   428032
#define WS_F2    436224

struct f2pair { float x, y; };              // align 4: legal 4B-aligned dwordx2

__device__ __forceinline__ unsigned short f2bf(float f) {
    unsigned u = __float_as_uint(f);
    return (unsigned short)((u + 0x7FFFu + ((u >> 16) & 1u)) >> 16);   // RNE
}
__device__ __forceinline__ float fast_rcp(float x) {
#if __has_builtin(__builtin_amdgcn_rcpf)
    return __builtin_amdgcn_rcpf(x);
#else
    return 1.0f / x;
#endif
}
__device__ __forceinline__ float fast_tanh(float x) {
    float t = __expf(2.0f * x);
    return 1.0f - 2.0f * fast_rcp(t + 1.0f);
}
__device__ __forceinline__ float fast_sigmoid(float x) {
    return fast_rcp(1.0f + __expf(-x));
}

// ---------------- prep: weight repack to frag-order bf16 (unchanged) --------
__global__ void prep_kernel(const float* __restrict__ w_c, const float* __restrict__ w_p,
                            const float* __restrict__ w_m, const float* __restrict__ w_conv,
                            const float* __restrict__ w_cd, unsigned short* __restrict__ ws) {
    int i = blockIdx.x * 256 + threadIdx.x;
    if (i >= 436224) return;
    float val;
    if (i < WS_APM) {                       // A_c: row=gmt*32+(l&31), k'=ks*16+(l>>5)*8+j
        int t = i, j = t & 7, l = (t >> 3) & 63, r = t >> 9, ks = r % 36, gmt = r / 36;
        int row = gmt * 32 + (l & 31);
        int kp = ks * 16 + (l >> 5) * 8 + j, tap = kp >> 6, ci = kp & 63;
        val = (row < 576) ? w_c[row * 576 + ci * 9 + tap] : 0.0f;
    } else if (i < WS_ACONV) {              // A_pm: rows 0-17 w_p, 18-26 w_m
        int t = i - WS_APM, j = t & 7, l = (t >> 3) & 63, ks = t >> 9;
        int row = l & 31;
        int kp = ks * 16 + (l >> 5) * 8 + j, tap = kp >> 6, ci = kp & 63;
        val = (row < 18) ? w_p[row * 576 + ci * 9 + tap]
            : (row < 27) ? w_m[(row - 18) * 576 + ci * 9 + tap] : 0.0f;
    } else if (i < WS_WCD) {                // A_conv: k = U-row (natural order)
        int t = i - WS_ACONV, j = t & 7, l = (t >> 3) & 63, r = t >> 9;
        int gks = r % 40, ocT = r / 40;
        int oc = ocT * 32 + (l & 31);
        int krow = gks * 16 + (l >> 5) * 8 + j;
        val = (krow < 576) ? w_conv[oc * 576 + krow] : 0.0f;
    } else {                                // Wcd row-major [64][128]
        val = w_cd[i - WS_WCD];
    }
    ws[i] = f2bf(val);
}

// ------ im2col B-stage (64-px, single 32-k' chunk): global->reg, reg->LDS ----
__device__ __forceinline__ uint4 stage_load64(const unsigned short* f2b, int h,
                                              int px0, int chunk, int tid) {
    int tap = chunk >> 1;
    int dh = tap / 3 - 1, dw = tap % 3 - 1;
    int hs = h + dh;
    int kg = tid >> 6, px = tid & 63;       // 256 tasks: kg(4) x px(64)
    int cg = (chunk & 1) * 4 + kg;          // channels cg*8 .. cg*8+7
    int wsrc = px0 + px + dw;
    uint4 pk = {0u, 0u, 0u, 0u};
    if (((unsigned)hs < 128u) && ((unsigned)wsrc < 128u))
        pk = *(const uint4*)(f2b + (((size_t)cg << 14) + (hs << 7) + wsrc) * 8);
    return pk;
}
__device__ __forceinline__ void stage_write64(char* Bst, uint4 pk, int tid) {
    int kg = tid >> 6, px = tid & 63;
    *(uint4*)(Bst + ((kg >> 1) * 2 + (px >> 5)) * 1024
                  + ((px & 31) + 32 * (kg & 1)) * 16) = pk;
}

// ---------------- k2: fused 1x1 conv -> fused2 cg-interleaved (unchanged) ----
__global__ __launch_bounds__(256, 4)
void k2_fused(const float* __restrict__ x, const float* __restrict__ ref,
              const float* __restrict__ b_cd, const unsigned short* __restrict__ wsbf,
              unsigned short* __restrict__ ws) {
    __shared__ __align__(16) char B0[32768];
    const int tid = threadIdx.x, l = tid & 63, w = tid >> 6;
    const int b = blockIdx.y, p0 = blockIdx.x * 128;
    const int rl31 = l & 31, kh8 = (l >> 5) * 8;

    #pragma unroll
    for (int it = 0; it < 8; ++it) {        // 2048 tasks: kg(16) x px(128)
        int task = it * 256 + tid;
        int kg = task >> 7, px = task & 127;
        const float* src = (kg < 8) ? x : ref;
        int kbase = (kg & 7) * 8;
        unsigned short v[8];
        #pragma unroll
        for (int j = 0; j < 8; ++j)
            v[j] = f2bf(src[(((size_t)b * 64 + kbase + j) << 14) + p0 + px]);
        uint4 pk;
        pk.x = (unsigned)v[0] | ((unsigned)v[1] << 16);
        pk.y = (unsigned)v[2] | ((unsigned)v[3] << 16);
        pk.z = (unsigned)v[4] | ((unsigned)v[5] << 16);
        pk.w = (unsigned)v[6] | ((unsigned)v[7] << 16);
        *(uint4*)(B0 + ((kg >> 1) * 4 + (px >> 5)) * 1024
                      + ((px & 31) + 32 * (kg & 1)) * 16) = pk;
    }
    __syncthreads();

    f32x16 a0, a1;
    #pragma unroll
    for (int r = 0; r < 16; ++r) { a0[r] = 0.0f; a1[r] = 0.0f; }
    const unsigned short* A0 = wsbf + WS_WCD + rl31 * 128 + kh8;
    #pragma unroll
    for (int s = 0; s < 8; ++s) {
        bf16x8 bf = *(bf16x8*)(B0 + ((s * 4 + w) * 64 + l) * 16);
        bf16x8 x0 = *(const bf16x8*)(A0 + s * 16);
        bf16x8 x1 = *(const bf16x8*)(A0 + 32 * 128 + s * 16);
        a0 = MFMA32(x0, bf, a0);
        a1 = MFMA32(x1, bf, a1);
    }
    unsigned short* f2 = ws + WS_F2 + ((size_t)b << 20);
    int px = p0 + w * 32 + rl31;
    int h4 = (l >> 5) * 4;
    #pragma unroll
    for (int t = 0; t < 2; ++t)
        #pragma unroll
        for (int q = 0; q < 4; ++q) {
            ushort4 st;
            float v0 = (t ? a1[q * 4 + 0] : a0[q * 4 + 0]) + b_cd[t * 32 + 8 * q + h4 + 0];
            float v1 = (t ? a1[q * 4 + 1] : a0[q * 4 + 1]) + b_cd[t * 32 + 8 * q + h4 + 1];
            float v2 = (t ? a1[q * 4 + 2] : a0[q * 4 + 2]) + b_cd[t * 32 + 8 * q + h4 + 2];
            float v3 = (t ? a1[q * 4 + 3] : a0[q * 4 + 3]) + b_cd[t * 32 + 8 * q + h4 + 3];
            st.x = f2bf(v0); st.y = f2bf(v1); st.z = f2bf(v2); st.w = f2bf(v3);
            *(ushort4*)(f2 + ((size_t)((t * 4 + q) << 14) + px) * 8 + h4) = st;
        }
}

// ---------------- k3: 64-px blocks, 5 thin m-passes, 48 acc regs ------------
__global__ __launch_bounds__(256, 4)
void k3_main(const float* __restrict__ x, const float* __restrict__ b_c,
             const float* __restrict__ b_p, const float* __restrict__ b_m,
             const unsigned short* __restrict__ wsbf, float* __restrict__ out) {
    __shared__ __align__(16) char lds[36096];
    char* Bst0 = lds;
    char* Bst1 = lds + 4096;
    char* Amod = lds + 8192;
    float* uL = (float*)(lds + 8192);       // 6.9K overlay; dead after tables
    short* sidx = (short*)(lds + 24576);
    unsigned short* w4h = (unsigned short*)(lds + 26880);
    float* mL = (float*)(lds + 31488);
    float* bcL = (float*)(lds + 33792);

    const int tid = threadIdx.x, l = tid & 63, w = tid >> 6;   // 4 waves
    // XCD-banded decode: xcd = id&7 owns h band [xcd*16, xcd*16+16) x b x half
    const int id = blockIdx.x;
    const int hbLin = (id & 7) * 128 + (id >> 3);
    const int half = hbLin & 1, b = (hbLin >> 1) & 3, h = hbLin >> 3;
    const int px0 = half * 64;
    const unsigned short* f2b = wsbf + WS_F2 + ((size_t)b << 20);

    for (int i = tid; i < 576; i += 256) bcL[i] = b_c[i];

    // ================= pm pre-phase: U_pm[27][64] =================
    {
        f32x16 pm;
        #pragma unroll
        for (int r = 0; r < 16; ++r) pm[r] = 0.0f;
        stage_write64(Bst0, stage_load64(f2b, h, px0, 0, tid), tid);
        __syncthreads();
        #pragma unroll 1
        for (int it = 0; it < 18; ++it) {
            char* cur = (it & 1) ? Bst1 : Bst0;
            char* nxt = (it & 1) ? Bst0 : Bst1;
            uint4 pk;
            if (it < 17) pk = stage_load64(f2b, h, px0, it + 1, tid);
            if (w < 2) {                    // wave w owns n-tile nt=w
                #pragma unroll
                for (int s = 0; s < 2; ++s) {
                    int ks = it * 2 + s;
                    bf16x8 bf = *(bf16x8*)(cur + ((s * 2 + w) * 64 + l) * 16);
                    bf16x8 apm = *(const bf16x8*)(wsbf + WS_APM + ((ks * 64 + l) << 3));
                    pm = MFMA32(apm, bf, pm);
                }
            }
            if (it < 17) stage_write64(nxt, pk, tid);
            __syncthreads();
        }
        if (w < 2) {                        // pm -> uL (f32), nt = w
            int pxp = w * 32 + (l & 31);
            #pragma unroll
            for (int reg = 0; reg < 16; ++reg) {
                int rl = (reg & 3) + 8 * (reg >> 2) + 4 * (l >> 5);
                uL[rl * 64 + pxp] = pm[reg];
            }
        }
        __syncthreads();
    }

    // ============ tables from uL: pair-based bilinear (once per block) =======
    #pragma unroll 1
    for (int i = tid; i < 576; i += 256) {
        int n = i >> 6, px = i & 63;
        float offr = uL[n * 64 + px] + b_p[n];
        float offc = uL[(9 + n) * 64 + px] + b_p[9 + n];
        float mraw = uL[(18 + n) * 64 + px] + b_m[n];
        int nr = n / 3, nc = n - nr * 3;
        float pr = (float)(h + nr) + offr;
        float pc = (float)(px0 + px + nc) + offc;
        float flr = floorf(pr), flc = floorf(pc);
        float prc = fminf(fmaxf(pr, 0.0f), 129.0f);
        float pcc = fminf(fmaxf(pc, 0.0f), 129.0f);
        // rows
        float q0r = fminf(fmaxf(flr, 0.0f), 129.0f);
        float q1r = fminf(fmaxf(flr + 1.0f, 0.0f), 129.0f);
        int ir0 = (int)q0r, ir1 = (int)q1r;
        bool vr0 = (ir0 >= 1) && (ir0 <= 128), vr1 = (ir1 >= 1) && (ir1 <= 128);
        float wr0 = vr0 ? (1.0f + q0r - prc) : 0.0f;
        float wr1 = vr1 ? (1.0f - (q1r - prc)) : 0.0f;
        // cols
        float q0c = fminf(fmaxf(flc, 0.0f), 129.0f);
        float q1c = fminf(fmaxf(flc + 1.0f, 0.0f), 129.0f);
        int ic0 = (int)q0c, ic1 = (int)q1c;
        bool vc0 = (ic0 >= 1) && (ic0 <= 128), vc1 = (ic1 >= 1) && (ic1 <= 128);
        float wc0 = vc0 ? (1.0f + q0c - pcc) : 0.0f;
        float wc1 = vc1 ? (1.0f - (q1c - pcc)) : 0.0f;
        // pair base in x-coords; fold clamp-remap + validity into slot weights
        int cx0 = ic0 - 1, cx1 = ic1 - 1;
        int base = min(max(cx0, 0), 126);
        float ws0 = ((base == cx0) && vc0 ? wc0 : 0.0f)
                  + ((base == cx1) && vc1 ? wc1 : 0.0f);
        float ws1 = ((base + 1 == cx0) && vc0 ? wc0 : 0.0f)
                  + ((base + 1 == cx1) && vc1 ? wc1 : 0.0f);
        int rx0 = min(max(ir0 - 1, 0), 127), rx1 = min(max(ir1 - 1, 0), 127);
        short2 s2;
        s2.x = (short)(rx0 * 128 + base);
        s2.y = (short)(rx1 * 128 + base);
        ((short2*)sidx)[px * 9 + n] = s2;
        int wb = (px * 9 + n) * 4;
        w4h[wb + 0] = __half_as_ushort(__float2half(wr0 * ws0));
        w4h[wb + 1] = __half_as_ushort(__float2half(wr0 * ws1));
        w4h[wb + 2] = __half_as_ushort(__float2half(wr1 * ws0));
        w4h[wb + 3] = __half_as_ushort(__float2half(wr1 * ws1));
        mL[n * 64 + px] = fast_sigmoid(mraw);
    }
    __syncthreads();

    // ================= 5 thin m-passes (1 m-tile/wave each) =================
    f32x16 oa;
    #pragma unroll
    for (int r = 0; r < 16; ++r) oa[r] = 0.0f;
    const float* xb = x + (((size_t)b * 64) << 14);
    const int ocT = w >> 1, nT2 = w & 1;

    #pragma unroll 1
    for (int p = 0; p < 5; ++p) {
        const int mt = p * 4 + w;           // exact 20 m-tiles over 5x4 waves
        f32x16 acc[2];                      // [nt], statically indexed
        #pragma unroll
        for (int j = 0; j < 2; ++j)
            #pragma unroll
            for (int r = 0; r < 16; ++r) acc[j][r] = 0.0f;

        // ---- U-GEMM k-loop: 18 dbuf iters, 4 MFMA/wave/iter ----
        stage_write64(Bst0, stage_load64(f2b, h, px0, 0, tid), tid);
        __syncthreads();
        #pragma unroll 1
        for (int it = 0; it < 18; ++it) {
            char* cur = (it & 1) ? Bst1 : Bst0;
            char* nxt = (it & 1) ? Bst0 : Bst1;
            uint4 pk;
            if (it < 17) pk = stage_load64(f2b, h, px0, it + 1, tid);
            #pragma unroll
            for (int s = 0; s < 2; ++s) {
                const int ks = it * 2 + s;
                bf16x8 bf0 = *(bf16x8*)(cur + ((s * 2 + 0) * 64 + l) * 16);
                bf16x8 bf1 = *(bf16x8*)(cur + ((s * 2 + 1) * 64 + l) * 16);
                bf16x8 af = *(const bf16x8*)(wsbf + WS_AC
                                + (((mt * 36 + ks) * 64 + l) << 3));
                acc[0] = MFMA32(af, bf0, acc[0]);
                acc[1] = MFMA32(af, bf1, acc[1]);
            }
            if (it < 17) stage_write64(nxt, pk, tid);
            __syncthreads();
        }

        // ---- epilogue: tanh + pair-load bilinear + modulate (in regs) ----
        const int rowbase = mt * 32;
        #pragma unroll
        for (int j = 0; j < 2; ++j) {
            const int pxe = j * 32 + (l & 31);
            if (rowbase < 576) {
                #pragma unroll
                for (int reg = 0; reg < 16; ++reg) {
                    int rl = (reg & 3) + 8 * (reg >> 2) + 4 * (l >> 5);
                    int row = rowbase + rl;
                    int c = row / 9, n = row - c * 9;
                    float uv = acc[j][reg] + bcL[row];
                    float t = fast_tanh(uv);
                    short2 s2 = ((short2*)sidx)[pxe * 9 + n];
                    int wb = (pxe * 9 + n) * 4;
                    float w0 = __half2float(__ushort_as_half(w4h[wb + 0]));
                    float w1 = __half2float(__ushort_as_half(w4h[wb + 1]));
                    float w2 = __half2float(__ushort_as_half(w4h[wb + 2]));
                    float w3 = __half2float(__ushort_as_half(w4h[wb + 3]));
                    const float* xp = xb + ((size_t)c << 14);
                    f2pair v0 = *(const f2pair*)(xp + s2.x);
                    f2pair v1 = *(const f2pair*)(xp + s2.y);
                    float samp = w0 * v0.x + w1 * v0.y + w2 * v1.x + w3 * v1.y;
                    acc[j][reg] = mL[n * 64 + pxe] * (samp + t);
                    // bound gather clustering: <=8 loads in flight
                    if ((reg & 3) == 3) __builtin_amdgcn_sched_barrier(0);
                }
            } else {
                #pragma unroll
                for (int reg = 0; reg < 16; ++reg) acc[j][reg] = 0.0f;
            }
        }

        // ---- scatter 128 rows -> Amod, then out-GEMM accumulate ----
        __syncthreads();                    // prev Amod reads (or tables) done
        #pragma unroll
        for (int j = 0; j < 2; ++j) {
            #pragma unroll
            for (int reg = 0; reg < 16; ++reg) {
                int rl = (reg & 3) + 8 * (reg >> 2) + 4 * (l >> 5);
                int k = w * 32 + rl;        // pass-local row in [0,128)
                *(unsigned short*)(Amod + ((k >> 4) * 2 + j) * 1024
                        + ((l & 31) + 32 * ((k >> 3) & 1)) * 16 + (k & 7) * 2)
                    = f2bf(acc[j][reg]);
            }
        }
        __syncthreads();
        #pragma unroll
        for (int ks8 = 0; ks8 < 8; ++ks8) {
            bf16x8 af = *(const bf16x8*)(wsbf + WS_ACONV
                            + (((ocT * 40 + p * 8 + ks8) * 64 + l) << 3));
            bf16x8 bf = *(bf16x8*)(Amod + (ks8 * 2 + nT2) * 1024 + l * 16);
            oa = MFMA32(af, bf, oa);
        }
    }

    // ---- final store: each out element written exactly once ----
    float* ob = out + (((size_t)b * 64) << 14) + (h << 7) + px0 + nT2 * 32 + (l & 31);
    #pragma unroll
    for (int reg = 0; reg < 16; ++reg) {
        int rl = (reg & 3) + 8 * (reg >> 2) + 4 * (l >> 5);
        int oc = ocT * 32 + rl;
        ob[(size_t)oc << 14] = oa[reg];
    }
}

extern "C" void kernel_launch(void* const* d_in, const int* in_sizes, int n_in,
                              void* d_out, int out_size, void* d_ws, size_t ws_size,
                              hipStream_t stream) {
    const float* x      = (const float*)d_in[0];
    const float* ref    = (const float*)d_in[1];
    const float* w_cd   = (const float*)d_in[2];
    const float* b_cd   = (const float*)d_in[3];
    const float* w_p    = (const float*)d_in[4];
    const float* b_p    = (const float*)d_in[5];
    const float* w_m    = (const float*)d_in[6];
    const float* b_m    = (const float*)d_in[7];
    const float* w_c    = (const float*)d_in[8];
    const float* b_c    = (const float*)d_in[9];
    const float* w_conv = (const float*)d_in[10];
    float* out = (float*)d_out;
    unsigned short* wsbf = (unsigned short*)d_ws;

    hipLaunchKernelGGL(prep_kernel, dim3(1704), dim3(256), 0, stream,
                       w_c, w_p, w_m, w_conv, w_cd, wsbf);
    hipLaunchKernelGGL(k2_fused, dim3(128, 4), dim3(256), 0, stream,
                       x, ref, b_cd, wsbf, wsbf);
    hipLaunchKernelGGL(k3_main, dim3(1024), dim3(256), 0, stream,
                       x, b_c, b_p, b_m, wsbf, out);
}